// Round 6
// baseline (747.793 us; speedup 1.0000x reference)
//
#include <hip/hip_runtime.h>

typedef __bf16 bf16_t;
typedef __bf16 bf16x8 __attribute__((ext_vector_type(8)));
typedef __bf16 bf16x4 __attribute__((ext_vector_type(4)));
typedef __bf16 bf16x2 __attribute__((ext_vector_type(2)));
typedef float  f32x4  __attribute__((ext_vector_type(4)));

#define MFMA16(a, b, c) __builtin_amdgcn_mfma_f32_16x16x32_bf16((a), (b), (c), 0, 0, 0)

// ---------------------------------------------------------------------------
// Fused weight prep: all 8 matrices in one launch.
// ---------------------------------------------------------------------------
__global__ __launch_bounds__(256) void prep_all_kernel(
    const float* __restrict__ nw,  const float* __restrict__ ew1,
    const float* __restrict__ ew2, const float* __restrict__ cw1,
    const float* __restrict__ cw2,
    bf16_t* __restrict__ nwt,  bf16_t* __restrict__ ew1t,
    bf16_t* __restrict__ ew2t, bf16_t* __restrict__ cw1t,
    bf16_t* __restrict__ cw2t)
{
    int b = blockIdx.x;
    const float* W; bf16_t* O; int Kact, KP, lb;
    if (b < 16)       { W = nw;  O = nwt;  Kact = 32;  KP = 32;  lb = b; }
    else if (b < 32)  { W = ew1; O = ew1t; Kact = 16;  KP = 32;  lb = b - 16; }
    else if (b < 96)  { W = ew2; O = ew2t; Kact = 128; KP = 128; lb = b - 32; }
    else if (b < 288) { int l = (b - 96) / 64;  W = cw1 + l * 16384; O = cw1t + l * 16384;
                        Kact = 128; KP = 128; lb = (b - 96) % 64; }
    else              { int l = (b - 288) / 64; W = cw2 + l * 16384; O = cw2t + l * 16384;
                        Kact = 128; KP = 128; lb = (b - 288) % 64; }
    int idx = lb * 256 + threadIdx.x;
    if (idx >= 128 * KP) return;
    int j    = idx & 7;
    int lane = (idx >> 3) & 63;
    int ct   = (idx >> 9) & 7;
    int kc   = idx >> 12;
    int n = ct * 16 + (lane & 15);
    int k = kc * 32 + (lane >> 4) * 8 + j;
    O[idx] = (bf16_t)((k < Kact) ? W[k * 128 + n] : 0.0f);
}

// ---------------------------------------------------------------------------
// CSR build; hist also warms edge_attr into the MALL.
// ---------------------------------------------------------------------------
__global__ __launch_bounds__(256) void hist_kernel(const int* __restrict__ ei,
                                                   int* __restrict__ deg, int E,
                                                   const float* __restrict__ ea) {
    int t = blockIdx.x * 256 + threadIdx.x;
    if (t < E) {
        atomicAdd(&deg[ei[(long)E + t]], 1);
        float w0 = ea[(long)t * 16];
        float w1 = ea[(long)t * 16 + 8];
        asm volatile("" :: "v"(w0), "v"(w1));
    }
}

__global__ __launch_bounds__(256) void scanA_kernel(const int* __restrict__ deg,
                                                    int* __restrict__ partials,
                                                    int* __restrict__ bsums, int N) {
    __shared__ int s[256];
    int b = blockIdx.x, t = threadIdx.x;
    int base = b * 1024 + t * 4;
    int v0 = (base + 0 < N) ? deg[base + 0] : 0;
    int v1 = (base + 1 < N) ? deg[base + 1] : 0;
    int v2 = (base + 2 < N) ? deg[base + 2] : 0;
    int v3 = (base + 3 < N) ? deg[base + 3] : 0;
    int local = v0 + v1 + v2 + v3;
    s[t] = local;
    __syncthreads();
    for (int off = 1; off < 256; off <<= 1) {
        int v = (t >= off) ? s[t - off] : 0;
        __syncthreads();
        s[t] += v;
        __syncthreads();
    }
    int excl = s[t] - local;
    if (base + 0 < N) partials[base + 0] = excl;
    if (base + 1 < N) partials[base + 1] = excl + v0;
    if (base + 2 < N) partials[base + 2] = excl + v0 + v1;
    if (base + 3 < N) partials[base + 3] = excl + v0 + v1 + v2;
    if (t == 255) bsums[b] = s[255];
}

__global__ __launch_bounds__(256) void scanB_kernel(const int* __restrict__ bsums,
                                                    int* __restrict__ boff,
                                                    int* __restrict__ rowptr,
                                                    int NB, int N) {
    __shared__ int s[256];
    int t = threadIdx.x;
    int local = (t < NB) ? bsums[t] : 0;
    s[t] = local;
    __syncthreads();
    for (int off = 1; off < 256; off <<= 1) {
        int v = (t >= off) ? s[t - off] : 0;
        __syncthreads();
        s[t] += v;
        __syncthreads();
    }
    if (t < NB) boff[t] = s[t] - local;
    if (t == NB - 1) rowptr[N] = s[t];
}

__global__ __launch_bounds__(256) void scanC_kernel(const int* __restrict__ partials,
                                                    const int* __restrict__ boff,
                                                    int* __restrict__ rowptr,
                                                    int* __restrict__ cursor, int N) {
    int i = blockIdx.x * 256 + threadIdx.x;
    if (i >= N) return;
    int v = partials[i] + boff[i >> 10];
    rowptr[i] = v;
    cursor[i] = v;
}

__global__ __launch_bounds__(256) void scatter_kernel(const int* __restrict__ ei,
                                                      int* __restrict__ cursor,
                                                      int* __restrict__ srcp,
                                                      int* __restrict__ eorig, int E) {
    int t = blockIdx.x * 256 + threadIdx.x;
    if (t >= E) return;
    int d = ei[(long)E + t];
    int pos = atomicAdd(&cursor[d], 1);
    srcp[pos] = ei[t];
    eorig[pos] = t;
}

// ---------------------------------------------------------------------------
// Node encoder: h = x[M,32] @ W + bias, out bf16. Barrier-free wave-private.
// ---------------------------------------------------------------------------
__global__ __launch_bounds__(256) void node_enc_kernel(
    const float* __restrict__ A, int M,
    const bf16_t* __restrict__ Ws, const float* __restrict__ bias,
    bf16_t* __restrict__ outp)
{
    constexpr int S = 136;
    __shared__ bf16_t T[128 * S];

    const int  tid  = threadIdx.x;
    const int  wv   = tid >> 6, lane = tid & 63;
    const long row0 = (long)blockIdx.x * 128;
    const int  l16  = lane & 15, quad = lane >> 4;

    {
        int r  = wv * 32 + (lane >> 1);
        long gr = row0 + r;
        int c0 = (lane & 1) * 16;
#pragma unroll
        for (int q = 0; q < 4; ++q) {
            float4 v = make_float4(0.f, 0.f, 0.f, 0.f);
            if (gr < M) v = *(const float4*)(A + gr * 32 + c0 + q * 4);
            bf16_t* d = &T[r * S + c0 + q * 4];
            d[0] = (bf16_t)v.x; d[1] = (bf16_t)v.y; d[2] = (bf16_t)v.z; d[3] = (bf16_t)v.w;
        }
    }

    f32x4 acc[2][8];
#pragma unroll
    for (int r = 0; r < 2; r++)
#pragma unroll
        for (int c = 0; c < 8; c++) acc[r][c] = (f32x4){0.f, 0.f, 0.f, 0.f};

    {
        bf16x8 af0 = *(const bf16x8*)&T[(wv * 32 + l16) * S + quad * 8];
        bf16x8 af1 = *(const bf16x8*)&T[(wv * 32 + 16 + l16) * S + quad * 8];
#pragma unroll
        for (int c = 0; c < 8; c++) {
            bf16x8 bfr = *(const bf16x8*)&Ws[((c * 64) + lane) * 8];
            acc[0][c] = MFMA16(af0, bfr, acc[0][c]);
            acc[1][c] = MFMA16(af1, bfr, acc[1][c]);
        }
    }

#pragma unroll
    for (int r = 0; r < 2; r++) {
        int mrow = wv * 32 + r * 16 + quad * 4;
#pragma unroll
        for (int c = 0; c < 8; c++) {
            int col = c * 16 + l16;
            float bb = bias[col];
#pragma unroll
            for (int q = 0; q < 4; q++)
                T[(mrow + q) * S + col] = (bf16_t)(acc[r][c][q] + bb);
        }
    }

#pragma unroll
    for (int it = 0; it < 8; ++it) {
        int idx = it * 64 + lane;
        int row = wv * 32 + (idx >> 4);
        int seg = idx & 15;
        long grow = row0 + row;
        if (grow < M)
            *(uint4*)&outp[grow * 128 + seg * 8] = *(const uint4*)&T[row * S + seg * 8];
    }
}

// ---------------------------------------------------------------------------
// Fused edge encoder, 64-row tiles, barrier-free wave-private flow.
// ---------------------------------------------------------------------------
__global__ __launch_bounds__(256) void edge_mlp_kernel(
    const float* __restrict__ A, int M,
    const bf16_t* __restrict__ Ws1, const float* __restrict__ b1,
    const bf16_t* __restrict__ Ws2, const float* __restrict__ b2,
    const int* __restrict__ eorig, bf16_t* __restrict__ outp)
{
    constexpr int S = 136;
    __shared__ bf16_t T[64 * S];

    const int  tid  = threadIdx.x;
    const int  wv   = tid >> 6, lane = tid & 63;
    const long row0 = (long)blockIdx.x * 64;
    const int  l16  = lane & 15, quad = lane >> 4;

    {
        int  r  = wv * 16 + (lane >> 2);
        long gr = row0 + r;
        float4 v = make_float4(0.f, 0.f, 0.f, 0.f);
        if (gr < M) {
            long eo = eorig[gr];
            v = *(const float4*)(A + eo * 16 + (lane & 3) * 4);
        }
        bf16_t* d = &T[r * S + (lane & 3) * 4];
        d[0] = (bf16_t)v.x; d[1] = (bf16_t)v.y; d[2] = (bf16_t)v.z; d[3] = (bf16_t)v.w;
    }

    f32x4 acc[8];
#pragma unroll
    for (int c = 0; c < 8; c++) acc[c] = (f32x4){0.f, 0.f, 0.f, 0.f};

    {   // stage 1: K=16
        bf16x8 af;
#pragma unroll
        for (int j = 0; j < 8; ++j) af[j] = (bf16_t)0.f;
        if (quad < 2) af = *(const bf16x8*)&T[(wv * 16 + l16) * S + quad * 8];
#pragma unroll
        for (int c = 0; c < 8; c++) {
            bf16x8 bfr = *(const bf16x8*)&Ws1[((c * 64) + lane) * 8];
            acc[c] = MFMA16(af, bfr, acc[c]);
        }
    }

    const int mbase = wv * 16 + quad * 4;

#pragma unroll
    for (int c = 0; c < 8; c++) {
        int col = c * 16 + l16;
        float bb = b1[col];
#pragma unroll
        for (int q = 0; q < 4; q++)
            T[(mbase + q) * S + col] = (bf16_t)fmaxf(acc[c][q] + bb, 0.f);
    }

#pragma unroll
    for (int c = 0; c < 8; c++) acc[c] = (f32x4){0.f, 0.f, 0.f, 0.f};

#pragma unroll
    for (int kc = 0; kc < 4; ++kc) {   // stage 2: K=128
        bf16x8 af = *(const bf16x8*)&T[(wv * 16 + l16) * S + kc * 32 + quad * 8];
#pragma unroll
        for (int c = 0; c < 8; c++) {
            bf16x8 bfr = *(const bf16x8*)&Ws2[(((kc * 8 + c) * 64) + lane) * 8];
            acc[c] = MFMA16(af, bfr, acc[c]);
        }
    }

#pragma unroll
    for (int c = 0; c < 8; c++) {
        int col = c * 16 + l16;
        float bb = b2[col];
#pragma unroll
        for (int q = 0; q < 4; q++)
            T[(mbase + q) * S + col] = (bf16_t)(acc[c][q] + bb);
    }

#pragma unroll
    for (int it = 0; it < 4; ++it) {
        int idx = it * 64 + lane;
        int row = wv * 16 + (idx >> 4);
        int seg = idx & 15;
        long grow = row0 + row;
        if (grow < M)
            *(uint4*)&outp[grow * 128 + seg * 8] = *(const uint4*)&T[row * S + seg * 8];
    }
}

// ---------------------------------------------------------------------------
// BN+relu materialization: hbuf = relu(z*sc+sh), bf16x8 per thread.
// ---------------------------------------------------------------------------
__global__ __launch_bounds__(256) void bnx_kernel(
    const bf16_t* __restrict__ z, const float* __restrict__ bns,
    const float* __restrict__ gamma, const float* __restrict__ beta,
    bf16_t* __restrict__ hbuf, int N)
{
    long t = (long)blockIdx.x * 256 + threadIdx.x;
    long i0 = t * 8;
    if (i0 >= (long)N * 128) return;
    int c = (int)(i0 & 127);
    const float invN = 1.f / (float)N;
    bf16x8 v = *(const bf16x8*)(z + i0);
    bf16x8 o;
#pragma unroll
    for (int u = 0; u < 8; ++u) {
        int cc = c + u;
        float m  = bns[cc] * invN;
        float va = bns[128 + cc] * invN - m * m;
        float iv = rsqrtf(va + 1e-5f);
        float sc = gamma[cc] * iv;
        float sh = beta[cc] - m * sc;
        o[u] = (bf16_t)fmaxf((float)v[u] * sc + sh, 0.f);
    }
    *(bf16x8*)(hbuf + i0) = o;
}

// ---------------------------------------------------------------------------
// FUSED aggregation + GINEConv MLP. PERSISTENT 256-thread blocks (8/CU,
// full 32 waves/CU) pulling 16-node tiles from an atomic cursor: removes
// the grid-tail that capped occupancy at 63%. Gather: 4 rows/wave, full
// wave per row, 8-edge batches (16 loads in flight/wave). MFMA: each of 4
// waves owns 2 col-tiles of the 16x128 output.
// ---------------------------------------------------------------------------
__global__ __launch_bounds__(256, 8) void aggr_conv_kernel(
    const bf16_t* __restrict__ xin,
    const bf16_t* __restrict__ e,
    const int* __restrict__ rowptr, const int* __restrict__ srcp, int M,
    int ntiles, int* __restrict__ tile_cursor,
    const bf16_t* __restrict__ Ws1, const float* __restrict__ b1,
    const bf16_t* __restrict__ Ws2, const float* __restrict__ b2,
    bf16_t* __restrict__ zout, float* __restrict__ bn_out)
{
    constexpr int S = 136;
    __shared__ bf16_t T[16 * S];
    __shared__ float  wred[256];
    __shared__ int    tileslot;

    const int tid  = threadIdx.x;
    const int wv   = tid >> 6, lane = tid & 63;
    const int l16  = lane & 15, quad = lane >> 4;

    for (;;) {
        if (tid == 0) tileslot = atomicAdd(tile_cursor, 1);
        __syncthreads();
        const int tile = tileslot;
        if (tile >= ntiles) return;
        const long row0 = (long)tile * 16;

        // preload this wave's 5 rowptr entries (rows row0+wv*4 .. +4)
        int rpv = 0;
        {
            long idx = row0 + wv * 4 + lane;
            if (idx > M) idx = M;
            if (lane <= 4) rpv = rowptr[idx];
        }

        // --- gather: 4 rows per wave, full wave per row, 2 cols/lane ---
#pragma unroll 1
        for (int ri = 0; ri < 4; ++ri) {
            const int  r   = wv * 4 + ri;
            const long n   = row0 + r;
            const int  beg = __shfl(rpv, ri);
            const int  end = __shfl(rpv, ri + 1);
            float ax = 0.f, ay = 0.f;
            if (n < M) {
                bf16x2 xv = *(const bf16x2*)(xin + n * 128 + lane * 2);
                ax = (float)xv[0]; ay = (float)xv[1];
                for (int base = beg; base < end; base += 64) {
                    int cnt = min(64, end - base);
                    int sv  = (base + lane < end) ? srcp[base + lane] : 0;
                    int j = 0;
                    for (; j + 7 < cnt; j += 8) {   // 16 loads in flight
                        int s0 = __shfl(sv, j),     s1 = __shfl(sv, j + 1);
                        int s2 = __shfl(sv, j + 2), s3 = __shfl(sv, j + 3);
                        int s4 = __shfl(sv, j + 4), s5 = __shfl(sv, j + 5);
                        int s6 = __shfl(sv, j + 6), s7 = __shfl(sv, j + 7);
                        bf16x2 x0 = *(const bf16x2*)(xin + (long)s0 * 128 + lane * 2);
                        bf16x2 x1 = *(const bf16x2*)(xin + (long)s1 * 128 + lane * 2);
                        bf16x2 x2 = *(const bf16x2*)(xin + (long)s2 * 128 + lane * 2);
                        bf16x2 x3 = *(const bf16x2*)(xin + (long)s3 * 128 + lane * 2);
                        bf16x2 x4 = *(const bf16x2*)(xin + (long)s4 * 128 + lane * 2);
                        bf16x2 x5 = *(const bf16x2*)(xin + (long)s5 * 128 + lane * 2);
                        bf16x2 x6 = *(const bf16x2*)(xin + (long)s6 * 128 + lane * 2);
                        bf16x2 x7 = *(const bf16x2*)(xin + (long)s7 * 128 + lane * 2);
                        bf16x2 e0 = *(const bf16x2*)(e + (long)(base + j + 0) * 128 + lane * 2);
                        bf16x2 e1 = *(const bf16x2*)(e + (long)(base + j + 1) * 128 + lane * 2);
                        bf16x2 e2 = *(const bf16x2*)(e + (long)(base + j + 2) * 128 + lane * 2);
                        bf16x2 e3 = *(const bf16x2*)(e + (long)(base + j + 3) * 128 + lane * 2);
                        bf16x2 e4 = *(const bf16x2*)(e + (long)(base + j + 4) * 128 + lane * 2);
                        bf16x2 e5 = *(const bf16x2*)(e + (long)(base + j + 5) * 128 + lane * 2);
                        bf16x2 e6 = *(const bf16x2*)(e + (long)(base + j + 6) * 128 + lane * 2);
                        bf16x2 e7 = *(const bf16x2*)(e + (long)(base + j + 7) * 128 + lane * 2);
                        ax += fmaxf((float)x0[0] + (float)e0[0], 0.f);
                        ay += fmaxf((float)x0[1] + (float)e0[1], 0.f);
                        ax += fmaxf((float)x1[0] + (float)e1[0], 0.f);
                        ay += fmaxf((float)x1[1] + (float)e1[1], 0.f);
                        ax += fmaxf((float)x2[0] + (float)e2[0], 0.f);
                        ay += fmaxf((float)x2[1] + (float)e2[1], 0.f);
                        ax += fmaxf((float)x3[0] + (float)e3[0], 0.f);
                        ay += fmaxf((float)x3[1] + (float)e3[1], 0.f);
                        ax += fmaxf((float)x4[0] + (float)e4[0], 0.f);
                        ay += fmaxf((float)x4[1] + (float)e4[1], 0.f);
                        ax += fmaxf((float)x5[0] + (float)e5[0], 0.f);
                        ay += fmaxf((float)x5[1] + (float)e5[1], 0.f);
                        ax += fmaxf((float)x6[0] + (float)e6[0], 0.f);
                        ay += fmaxf((float)x6[1] + (float)e6[1], 0.f);
                        ax += fmaxf((float)x7[0] + (float)e7[0], 0.f);
                        ay += fmaxf((float)x7[1] + (float)e7[1], 0.f);
                    }
                    for (; j + 3 < cnt; j += 4) {
                        int s0 = __shfl(sv, j),     s1 = __shfl(sv, j + 1);
                        int s2 = __shfl(sv, j + 2), s3 = __shfl(sv, j + 3);
                        bf16x2 x0 = *(const bf16x2*)(xin + (long)s0 * 128 + lane * 2);
                        bf16x2 x1 = *(const bf16x2*)(xin + (long)s1 * 128 + lane * 2);
                        bf16x2 x2 = *(const bf16x2*)(xin + (long)s2 * 128 + lane * 2);
                        bf16x2 x3 = *(const bf16x2*)(xin + (long)s3 * 128 + lane * 2);
                        bf16x2 e0 = *(const bf16x2*)(e + (long)(base + j + 0) * 128 + lane * 2);
                        bf16x2 e1 = *(const bf16x2*)(e + (long)(base + j + 1) * 128 + lane * 2);
                        bf16x2 e2 = *(const bf16x2*)(e + (long)(base + j + 2) * 128 + lane * 2);
                        bf16x2 e3 = *(const bf16x2*)(e + (long)(base + j + 3) * 128 + lane * 2);
                        ax += fmaxf((float)x0[0] + (float)e0[0], 0.f);
                        ay += fmaxf((float)x0[1] + (float)e0[1], 0.f);
                        ax += fmaxf((float)x1[0] + (float)e1[0], 0.f);
                        ay += fmaxf((float)x1[1] + (float)e1[1], 0.f);
                        ax += fmaxf((float)x2[0] + (float)e2[0], 0.f);
                        ay += fmaxf((float)x2[1] + (float)e2[1], 0.f);
                        ax += fmaxf((float)x3[0] + (float)e3[0], 0.f);
                        ay += fmaxf((float)x3[1] + (float)e3[1], 0.f);
                    }
                    for (; j < cnt; ++j) {
                        int s0 = __shfl(sv, j);
                        bf16x2 x0 = *(const bf16x2*)(xin + (long)s0 * 128 + lane * 2);
                        bf16x2 e0 = *(const bf16x2*)(e + (long)(base + j) * 128 + lane * 2);
                        ax += fmaxf((float)x0[0] + (float)e0[0], 0.f);
                        ay += fmaxf((float)x0[1] + (float)e0[1], 0.f);
                    }
                }
            }
            bf16x2 o; o[0] = (bf16_t)ax; o[1] = (bf16_t)ay;
            *(bf16x2*)&T[r * S + lane * 2] = o;
        }
        __syncthreads();

        // --- MFMA: wave wv owns col-tiles 2wv, 2wv+1 over all 16 rows ---
        const int mbase = quad * 4;

        f32x4 acc[2];
#pragma unroll
        for (int c = 0; c < 2; c++) acc[c] = (f32x4){0.f, 0.f, 0.f, 0.f};

#pragma unroll
        for (int kc = 0; kc < 4; ++kc) {
            bf16x8 af = *(const bf16x8*)&T[l16 * S + kc * 32 + quad * 8];
#pragma unroll
            for (int c = 0; c < 2; c++) {
                int ct = wv * 2 + c;
                bf16x8 bfr = *(const bf16x8*)&Ws1[(((kc * 8 + ct) * 64) + lane) * 8];
                acc[c] = MFMA16(af, bfr, acc[c]);
            }
        }
        __syncthreads();   // done reading aggr tile

#pragma unroll
        for (int c = 0; c < 2; c++) {
            int col = (wv * 2 + c) * 16 + l16;
            float bb = b1[col];
#pragma unroll
            for (int q = 0; q < 4; q++)
                T[(mbase + q) * S + col] = (bf16_t)fmaxf(acc[c][q] + bb, 0.f);
        }
        __syncthreads();   // H complete

#pragma unroll
        for (int c = 0; c < 2; c++) acc[c] = (f32x4){0.f, 0.f, 0.f, 0.f};

#pragma unroll
        for (int kc = 0; kc < 4; ++kc) {
            bf16x8 af = *(const bf16x8*)&T[l16 * S + kc * 32 + quad * 8];
#pragma unroll
            for (int c = 0; c < 2; c++) {
                int ct = wv * 2 + c;
                bf16x8 bfr = *(const bf16x8*)&Ws2[(((kc * 8 + ct) * 64) + lane) * 8];
                acc[c] = MFMA16(af, bfr, acc[c]);
            }
        }
        __syncthreads();   // done reading H

        // Z epilogue: write Z to LDS, per-col stats into wred
#pragma unroll
        for (int c = 0; c < 2; c++) {
            int col = (wv * 2 + c) * 16 + l16;
            float bb = b2[col];
            float s = 0.f, s2 = 0.f;
#pragma unroll
            for (int q = 0; q < 4; q++) {
                float v = acc[c][q] + bb;
                T[(mbase + q) * S + col] = (bf16_t)v;
                if (row0 + mbase + q < M) { s += v; s2 += v * v; }
            }
            s  += __shfl_xor(s, 16);  s  += __shfl_xor(s, 32);
            s2 += __shfl_xor(s2, 16); s2 += __shfl_xor(s2, 32);
            if (quad == 0) {
                wred[col]       = s;
                wred[128 + col] = s2;
            }
        }
        __syncthreads();   // Z + wred complete

        // global Z write: 256 threads x 1 uint4 = 16 rows x 16 segs
        {
            int row = tid >> 4, seg = tid & 15;
            long grow = row0 + row;
            if (grow < M)
                *(uint4*)&zout[grow * 128 + seg * 8] = *(const uint4*)&T[row * S + seg * 8];
        }
        atomicAdd(&bn_out[tid], wred[tid]);
        __syncthreads();   // protect T/wred/tileslot reuse
    }
}

// ---------------------------------------------------------------------------
// Mean-pool over sorted batch; derives final-layer BN inline.
// ---------------------------------------------------------------------------
__global__ __launch_bounds__(128) void pool_kernel(
    const bf16_t* __restrict__ z, const float* __restrict__ bns,
    const float* __restrict__ gamma, const float* __restrict__ beta,
    const int* __restrict__ batch,
    float* __restrict__ gsum, float* __restrict__ cnt, int N)
{
    int c = threadIdx.x;
    float mean = bns[c] / (float)N;
    float var  = bns[128 + c] / (float)N - mean * mean;
    float inv  = rsqrtf(var + 1e-5f);
    float sc   = gamma[c] * inv;
    float sh   = beta[c] - mean * sc;
    int n0 = blockIdx.x * 32;
    int n1 = min(n0 + 32, N);
    float acc = 0.f;
    int cur = -1, rc = 0;
    for (int n = n0; n < n1; ++n) {
        int g = batch[n];
        if (g != cur) {
            if (cur >= 0) {
                atomicAdd(&gsum[(long)cur * 128 + c], acc);
                if (c == 0) atomicAdd(&cnt[cur], (float)rc);
            }
            cur = g; acc = 0.f; rc = 0;
        }
        acc += fmaxf((float)z[(long)n * 128 + c] * sc + sh, 0.f);
        rc++;
    }
    if (cur >= 0) {
        atomicAdd(&gsum[(long)cur * 128 + c], acc);
        if (c == 0) atomicAdd(&cnt[cur], (float)rc);
    }
}

__global__ __launch_bounds__(128) void head_kernel(
    const float* __restrict__ gsum, const float* __restrict__ cnt,
    const float* __restrict__ ext_in,
    const float* __restrict__ ew1, const float* __restrict__ eb1,
    const float* __restrict__ ew2, const float* __restrict__ eb2,
    const float* __restrict__ rw1, const float* __restrict__ rb1,
    const float* __restrict__ rw2, const float* __restrict__ rb2,
    float* __restrict__ out)
{
    int g = blockIdx.x, c = threadIdx.x;
    __shared__ float sx[8];
    __shared__ float h1[128];
    __shared__ float comb[256];
    __shared__ float red[128];

    if (c < 8) sx[c] = ext_in[g * 8 + c];
    __syncthreads();
    float a = eb1[c];
#pragma unroll
    for (int k = 0; k < 8; k++) a += sx[k] * ew1[k * 128 + c];
    h1[c] = fmaxf(a, 0.f);
    __syncthreads();
    float b = eb2[c];
    for (int k = 0; k < 128; k++) b += h1[k] * ew2[k * 128 + c];
    comb[c]       = gsum[(long)g * 128 + c] / fmaxf(cnt[g], 1.0f);
    comb[128 + c] = b;
    __syncthreads();
    float r = rb1[c];
    for (int k = 0; k < 256; k++) r += comb[k] * rw1[k * 128 + c];
    r = fmaxf(r, 0.f);
    red[c] = r * rw2[c];
    __syncthreads();
    if (c == 0) {
        float s = rb2[0];
        for (int k = 0; k < 128; k++) s += red[k];
        out[g] = s;
    }
}

// ---------------------------------------------------------------------------
extern "C" void kernel_launch(void* const* d_in, const int* in_sizes, int n_in,
                              void* d_out, int out_size, void* d_ws, size_t ws_size,
                              hipStream_t stream)
{
    const float* x         = (const float*)d_in[0];
    const float* edge_attr = (const float*)d_in[1];
    const float* externals = (const float*)d_in[2];
    const float* node_w    = (const float*)d_in[3];
    const float* node_b    = (const float*)d_in[4];
    const float* ee_w1     = (const float*)d_in[5];
    const float* ee_b1     = (const float*)d_in[6];
    const float* ee_w2     = (const float*)d_in[7];
    const float* ee_b2     = (const float*)d_in[8];
    const float* conv_w1   = (const float*)d_in[9];
    const float* conv_b1   = (const float*)d_in[10];
    const float* conv_w2   = (const float*)d_in[11];
    const float* conv_b2   = (const float*)d_in[12];
    const float* bn_gamma  = (const float*)d_in[13];
    const float* bn_beta   = (const float*)d_in[14];
    const float* ext_w1    = (const float*)d_in[15];
    const float* ext_b1    = (const float*)d_in[16];
    const float* ext_w2    = (const float*)d_in[17];
    const float* ext_b2    = (const float*)d_in[18];
    const float* reg_w1    = (const float*)d_in[19];
    const float* reg_b1    = (const float*)d_in[20];
    const float* reg_w2    = (const float*)d_in[21];
    const float* reg_b2    = (const float*)d_in[22];
    const int* edge_index  = (const int*)d_in[23];
    const int* batch       = (const int*)d_in[24];

    const int N = in_sizes[0] / 32;
    const int E = in_sizes[1] / 16;
    const int G = in_sizes[2] / 8;
    const int NB = (N + 1023) / 1024;

    char* p = (char*)d_ws;
    auto alloc = [&](size_t bytes) -> void* {
        void* r = (void*)p;
        p += (bytes + 255) & ~(size_t)255;
        return r;
    };
    bf16_t* h       = (bf16_t*)alloc((size_t)N * 128 * 2);
    bf16_t* zA      = (bf16_t*)alloc((size_t)N * 128 * 2);
    bf16_t* zB      = (bf16_t*)alloc((size_t)N * 128 * 2);
    bf16_t* hb      = (bf16_t*)alloc((size_t)N * 128 * 2);   // BN-activated nodes
    bf16_t* ebuf    = (bf16_t*)alloc((size_t)E * 128 * 2);   // dst-sorted
    int*    deg     = (int*)alloc((size_t)N * 4);
    int*    rowptr  = (int*)alloc(((size_t)N + 1) * 4);
    int*    cursor  = (int*)alloc((size_t)N * 4);
    int*    partials= (int*)alloc((size_t)N * 4);
    int*    bsums   = (int*)alloc((size_t)NB * 4);
    int*    boff    = (int*)alloc((size_t)NB * 4);
    int*    srcp    = (int*)alloc((size_t)E * 4);
    int*    eorig   = (int*)alloc((size_t)E * 4);
    bf16_t* node_wt = (bf16_t*)alloc(128 * 32 * 2);
    bf16_t* ee_w1t  = (bf16_t*)alloc(128 * 32 * 2);
    bf16_t* ee_w2t  = (bf16_t*)alloc(128 * 128 * 2);
    bf16_t* cw1t    = (bf16_t*)alloc(3 * 128 * 128 * 2);
    bf16_t* cw2t    = (bf16_t*)alloc(3 * 128 * 128 * 2);
    float*  bns     = (float*)alloc(3 * 256 * 4);            // per-layer BN sums
    int*    tcur    = (int*)alloc(3 * 4);                    // tile cursors
    float*  gsum    = (float*)alloc((size_t)G * 128 * 4);
    float*  cnt     = (float*)alloc((size_t)G * 4);

    // --- CSR build (by dst); hist also warms edge_attr into MALL ---
    hipMemsetAsync(deg, 0, (size_t)N * 4, stream);
    hipMemsetAsync(bns, 0, 3 * 256 * 4, stream);
    hipMemsetAsync(tcur, 0, 3 * 4, stream);
    hist_kernel<<<(E + 255) / 256, 256, 0, stream>>>(edge_index, deg, E, edge_attr);
    scanA_kernel<<<NB, 256, 0, stream>>>(deg, partials, bsums, N);
    scanB_kernel<<<1, 256, 0, stream>>>(bsums, boff, rowptr, NB, N);
    scanC_kernel<<<(N + 255) / 256, 256, 0, stream>>>(partials, boff, rowptr, cursor, N);
    scatter_kernel<<<(E + 255) / 256, 256, 0, stream>>>(edge_index, cursor, srcp, eorig, E);

    // --- weight prep (single launch) ---
    prep_all_kernel<<<480, 256, 0, stream>>>(node_w, ee_w1, ee_w2, conv_w1, conv_w2,
                                             node_wt, ee_w1t, ee_w2t, cw1t, cw2t);

    // --- node encoder ---
    node_enc_kernel<<<(N + 127) / 128, 256, 0, stream>>>(x, N, node_wt, node_b, h);

    // --- edge encoder, CSR-order compute, sequential write ---
    edge_mlp_kernel<<<(E + 63) / 64, 256, 0, stream>>>(
        edge_attr, E, ee_w1t, ee_b1, ee_w2t, ee_b2, eorig, ebuf);

    // --- GINE layers (activation pre-materialized via bnx) ---
    const int ntiles = (N + 15) / 16;
    const int pblk   = min(ntiles, 2048);   // 8 blocks/CU capacity
    const int bblk = ((N * 128 / 8) + 255) / 256;
    aggr_conv_kernel<<<pblk, 256, 0, stream>>>(
        h, ebuf, rowptr, srcp, N, ntiles, tcur + 0,
        cw1t + 0 * 16384, conv_b1 + 0 * 128, cw2t + 0 * 16384, conv_b2 + 0 * 128,
        zA, bns + 0);
    bnx_kernel<<<bblk, 256, 0, stream>>>(zA, bns + 0, bn_gamma + 0, bn_beta + 0, hb, N);
    aggr_conv_kernel<<<pblk, 256, 0, stream>>>(
        hb, ebuf, rowptr, srcp, N, ntiles, tcur + 1,
        cw1t + 1 * 16384, conv_b1 + 1 * 128, cw2t + 1 * 16384, conv_b2 + 1 * 128,
        zB, bns + 256);
    bnx_kernel<<<bblk, 256, 0, stream>>>(zB, bns + 256, bn_gamma + 128, bn_beta + 128, hb, N);
    aggr_conv_kernel<<<pblk, 256, 0, stream>>>(
        hb, ebuf, rowptr, srcp, N, ntiles, tcur + 2,
        cw1t + 2 * 16384, conv_b1 + 2 * 128, cw2t + 2 * 16384, conv_b2 + 2 * 128,
        zA, bns + 512);

    // --- pooling (BN+relu applied on read) + head ---
    hipMemsetAsync(gsum, 0, (size_t)G * 128 * 4, stream);
    hipMemsetAsync(cnt, 0, (size_t)G * 4, stream);
    pool_kernel<<<(N + 31) / 32, 128, 0, stream>>>(zA, bns + 512, bn_gamma + 256, bn_beta + 256,
                                                   batch, gsum, cnt, N);
    head_kernel<<<G, 128, 0, stream>>>(gsum, cnt, externals,
                                       ext_w1, ext_b1, ext_w2, ext_b2,
                                       reg_w1, reg_b1, reg_w2, reg_b2,
                                       (float*)d_out);
}

// Round 7
// 549.465 us; speedup vs baseline: 1.3609x; 1.3609x over previous
//
#include <hip/hip_runtime.h>

typedef __bf16 bf16_t;
typedef __bf16 bf16x8 __attribute__((ext_vector_type(8)));
typedef __bf16 bf16x4 __attribute__((ext_vector_type(4)));
typedef __bf16 bf16x2 __attribute__((ext_vector_type(2)));
typedef float  f32x4  __attribute__((ext_vector_type(4)));

#define MFMA16(a, b, c) __builtin_amdgcn_mfma_f32_16x16x32_bf16((a), (b), (c), 0, 0, 0)

// ---------------------------------------------------------------------------
// Fused weight prep: all 8 matrices in one launch.
// ---------------------------------------------------------------------------
__global__ __launch_bounds__(256) void prep_all_kernel(
    const float* __restrict__ nw,  const float* __restrict__ ew1,
    const float* __restrict__ ew2, const float* __restrict__ cw1,
    const float* __restrict__ cw2,
    bf16_t* __restrict__ nwt,  bf16_t* __restrict__ ew1t,
    bf16_t* __restrict__ ew2t, bf16_t* __restrict__ cw1t,
    bf16_t* __restrict__ cw2t)
{
    int b = blockIdx.x;
    const float* W; bf16_t* O; int Kact, KP, lb;
    if (b < 16)       { W = nw;  O = nwt;  Kact = 32;  KP = 32;  lb = b; }
    else if (b < 32)  { W = ew1; O = ew1t; Kact = 16;  KP = 32;  lb = b - 16; }
    else if (b < 96)  { W = ew2; O = ew2t; Kact = 128; KP = 128; lb = b - 32; }
    else if (b < 288) { int l = (b - 96) / 64;  W = cw1 + l * 16384; O = cw1t + l * 16384;
                        Kact = 128; KP = 128; lb = (b - 96) % 64; }
    else              { int l = (b - 288) / 64; W = cw2 + l * 16384; O = cw2t + l * 16384;
                        Kact = 128; KP = 128; lb = (b - 288) % 64; }
    int idx = lb * 256 + threadIdx.x;
    if (idx >= 128 * KP) return;
    int j    = idx & 7;
    int lane = (idx >> 3) & 63;
    int ct   = (idx >> 9) & 7;
    int kc   = idx >> 12;
    int n = ct * 16 + (lane & 15);
    int k = kc * 32 + (lane >> 4) * 8 + j;
    O[idx] = (bf16_t)((k < Kact) ? W[k * 128 + n] : 0.0f);
}

// ---------------------------------------------------------------------------
// CSR build; hist also warms edge_attr into the MALL.
// ---------------------------------------------------------------------------
__global__ __launch_bounds__(256) void hist_kernel(const int* __restrict__ ei,
                                                   int* __restrict__ deg, int E,
                                                   const float* __restrict__ ea) {
    int t = blockIdx.x * 256 + threadIdx.x;
    if (t < E) {
        atomicAdd(&deg[ei[(long)E + t]], 1);
        float w0 = ea[(long)t * 16];
        float w1 = ea[(long)t * 16 + 8];
        asm volatile("" :: "v"(w0), "v"(w1));
    }
}

__global__ __launch_bounds__(256) void scanA_kernel(const int* __restrict__ deg,
                                                    int* __restrict__ partials,
                                                    int* __restrict__ bsums, int N) {
    __shared__ int s[256];
    int b = blockIdx.x, t = threadIdx.x;
    int base = b * 1024 + t * 4;
    int v0 = (base + 0 < N) ? deg[base + 0] : 0;
    int v1 = (base + 1 < N) ? deg[base + 1] : 0;
    int v2 = (base + 2 < N) ? deg[base + 2] : 0;
    int v3 = (base + 3 < N) ? deg[base + 3] : 0;
    int local = v0 + v1 + v2 + v3;
    s[t] = local;
    __syncthreads();
    for (int off = 1; off < 256; off <<= 1) {
        int v = (t >= off) ? s[t - off] : 0;
        __syncthreads();
        s[t] += v;
        __syncthreads();
    }
    int excl = s[t] - local;
    if (base + 0 < N) partials[base + 0] = excl;
    if (base + 1 < N) partials[base + 1] = excl + v0;
    if (base + 2 < N) partials[base + 2] = excl + v0 + v1;
    if (base + 3 < N) partials[base + 3] = excl + v0 + v1 + v2;
    if (t == 255) bsums[b] = s[255];
}

__global__ __launch_bounds__(256) void scanB_kernel(const int* __restrict__ bsums,
                                                    int* __restrict__ boff,
                                                    int* __restrict__ rowptr,
                                                    int NB, int N) {
    __shared__ int s[256];
    int t = threadIdx.x;
    int local = (t < NB) ? bsums[t] : 0;
    s[t] = local;
    __syncthreads();
    for (int off = 1; off < 256; off <<= 1) {
        int v = (t >= off) ? s[t - off] : 0;
        __syncthreads();
        s[t] += v;
        __syncthreads();
    }
    if (t < NB) boff[t] = s[t] - local;
    if (t == NB - 1) rowptr[N] = s[t];
}

__global__ __launch_bounds__(256) void scanC_kernel(const int* __restrict__ partials,
                                                    const int* __restrict__ boff,
                                                    int* __restrict__ rowptr,
                                                    int* __restrict__ cursor, int N) {
    int i = blockIdx.x * 256 + threadIdx.x;
    if (i >= N) return;
    int v = partials[i] + boff[i >> 10];
    rowptr[i] = v;
    cursor[i] = v;
}

// scatter now also records epos[t] = CSR slot of original edge t
__global__ __launch_bounds__(256) void scatter_kernel(const int* __restrict__ ei,
                                                      int* __restrict__ cursor,
                                                      int* __restrict__ srcp,
                                                      int* __restrict__ epos, int E) {
    int t = blockIdx.x * 256 + threadIdx.x;
    if (t >= E) return;
    int d = ei[(long)E + t];
    int pos = atomicAdd(&cursor[d], 1);
    srcp[pos] = ei[t];
    epos[t] = pos;
}

// ---------------------------------------------------------------------------
// Node encoder: h = x[M,32] @ W + bias, out bf16. Barrier-free wave-private.
// ---------------------------------------------------------------------------
__global__ __launch_bounds__(256) void node_enc_kernel(
    const float* __restrict__ A, int M,
    const bf16_t* __restrict__ Ws, const float* __restrict__ bias,
    bf16_t* __restrict__ outp)
{
    constexpr int S = 136;
    __shared__ bf16_t T[128 * S];

    const int  tid  = threadIdx.x;
    const int  wv   = tid >> 6, lane = tid & 63;
    const long row0 = (long)blockIdx.x * 128;
    const int  l16  = lane & 15, quad = lane >> 4;

    {
        int r  = wv * 32 + (lane >> 1);
        long gr = row0 + r;
        int c0 = (lane & 1) * 16;
#pragma unroll
        for (int q = 0; q < 4; ++q) {
            float4 v = make_float4(0.f, 0.f, 0.f, 0.f);
            if (gr < M) v = *(const float4*)(A + gr * 32 + c0 + q * 4);
            bf16_t* d = &T[r * S + c0 + q * 4];
            d[0] = (bf16_t)v.x; d[1] = (bf16_t)v.y; d[2] = (bf16_t)v.z; d[3] = (bf16_t)v.w;
        }
    }

    f32x4 acc[2][8];
#pragma unroll
    for (int r = 0; r < 2; r++)
#pragma unroll
        for (int c = 0; c < 8; c++) acc[r][c] = (f32x4){0.f, 0.f, 0.f, 0.f};

    {
        bf16x8 af0 = *(const bf16x8*)&T[(wv * 32 + l16) * S + quad * 8];
        bf16x8 af1 = *(const bf16x8*)&T[(wv * 32 + 16 + l16) * S + quad * 8];
#pragma unroll
        for (int c = 0; c < 8; c++) {
            bf16x8 bfr = *(const bf16x8*)&Ws[((c * 64) + lane) * 8];
            acc[0][c] = MFMA16(af0, bfr, acc[0][c]);
            acc[1][c] = MFMA16(af1, bfr, acc[1][c]);
        }
    }

#pragma unroll
    for (int r = 0; r < 2; r++) {
        int mrow = wv * 32 + r * 16 + quad * 4;
#pragma unroll
        for (int c = 0; c < 8; c++) {
            int col = c * 16 + l16;
            float bb = bias[col];
#pragma unroll
            for (int q = 0; q < 4; q++)
                T[(mrow + q) * S + col] = (bf16_t)(acc[r][c][q] + bb);
        }
    }

#pragma unroll
    for (int it = 0; it < 8; ++it) {
        int idx = it * 64 + lane;
        int row = wv * 32 + (idx >> 4);
        int seg = idx & 15;
        long grow = row0 + row;
        if (grow < M)
            *(uint4*)&outp[grow * 128 + seg * 8] = *(const uint4*)&T[row * S + seg * 8];
    }
}

// ---------------------------------------------------------------------------
// Fused edge encoder, 64-row tiles, barrier-free wave-private flow.
// NEW: sequential edge_attr read (original order) + SCATTER-WRITE to the
// CSR slot (epos). Random access moved from blocking reads to
// fire-and-forget writes; waves never stall on the scatter.
// ---------------------------------------------------------------------------
__global__ __launch_bounds__(256) void edge_mlp_kernel(
    const float* __restrict__ A, int M,
    const bf16_t* __restrict__ Ws1, const float* __restrict__ b1,
    const bf16_t* __restrict__ Ws2, const float* __restrict__ b2,
    const int* __restrict__ epos, bf16_t* __restrict__ outp)
{
    constexpr int S = 136;
    __shared__ bf16_t T[64 * S];

    const int  tid  = threadIdx.x;
    const int  wv   = tid >> 6, lane = tid & 63;
    const long row0 = (long)blockIdx.x * 64;
    const int  l16  = lane & 15, quad = lane >> 4;

    {   // sequential coalesced load: 4 lanes per row, one float4 per lane
        int  r  = wv * 16 + (lane >> 2);
        long gr = row0 + r;
        float4 v = make_float4(0.f, 0.f, 0.f, 0.f);
        if (gr < M) v = *(const float4*)(A + gr * 16 + (lane & 3) * 4);
        bf16_t* d = &T[r * S + (lane & 3) * 4];
        d[0] = (bf16_t)v.x; d[1] = (bf16_t)v.y; d[2] = (bf16_t)v.z; d[3] = (bf16_t)v.w;
    }

    f32x4 acc[8];
#pragma unroll
    for (int c = 0; c < 8; c++) acc[c] = (f32x4){0.f, 0.f, 0.f, 0.f};

    {   // stage 1: K=16
        bf16x8 af;
#pragma unroll
        for (int j = 0; j < 8; ++j) af[j] = (bf16_t)0.f;
        if (quad < 2) af = *(const bf16x8*)&T[(wv * 16 + l16) * S + quad * 8];
#pragma unroll
        for (int c = 0; c < 8; c++) {
            bf16x8 bfr = *(const bf16x8*)&Ws1[((c * 64) + lane) * 8];
            acc[c] = MFMA16(af, bfr, acc[c]);
        }
    }

    const int mbase = wv * 16 + quad * 4;

#pragma unroll
    for (int c = 0; c < 8; c++) {
        int col = c * 16 + l16;
        float bb = b1[col];
#pragma unroll
        for (int q = 0; q < 4; q++)
            T[(mbase + q) * S + col] = (bf16_t)fmaxf(acc[c][q] + bb, 0.f);
    }

#pragma unroll
    for (int c = 0; c < 8; c++) acc[c] = (f32x4){0.f, 0.f, 0.f, 0.f};

#pragma unroll
    for (int kc = 0; kc < 4; ++kc) {   // stage 2: K=128
        bf16x8 af = *(const bf16x8*)&T[(wv * 16 + l16) * S + kc * 32 + quad * 8];
#pragma unroll
        for (int c = 0; c < 8; c++) {
            bf16x8 bfr = *(const bf16x8*)&Ws2[(((kc * 8 + c) * 64) + lane) * 8];
            acc[c] = MFMA16(af, bfr, acc[c]);
        }
    }

#pragma unroll
    for (int c = 0; c < 8; c++) {
        int col = c * 16 + l16;
        float bb = b2[col];
#pragma unroll
        for (int q = 0; q < 4; q++)
            T[(mbase + q) * S + col] = (bf16_t)(acc[c][q] + bb);
    }

    // scatter store: own 16 rows, 4 uint4 per lane, to CSR slots
#pragma unroll
    for (int it = 0; it < 4; ++it) {
        int idx = it * 64 + lane;
        int row = wv * 16 + (idx >> 4);
        int seg = idx & 15;
        long grow = row0 + row;
        if (grow < M) {
            long pos = epos[grow];
            *(uint4*)&outp[pos * 128 + seg * 8] = *(const uint4*)&T[row * S + seg * 8];
        }
    }
}

// ---------------------------------------------------------------------------
// BN+relu materialization: hbuf = relu(z*sc+sh), bf16x8 per thread.
// ---------------------------------------------------------------------------
__global__ __launch_bounds__(256) void bnx_kernel(
    const bf16_t* __restrict__ z, const float* __restrict__ bns,
    const float* __restrict__ gamma, const float* __restrict__ beta,
    bf16_t* __restrict__ hbuf, int N)
{
    long t = (long)blockIdx.x * 256 + threadIdx.x;
    long i0 = t * 8;
    if (i0 >= (long)N * 128) return;
    int c = (int)(i0 & 127);
    const float invN = 1.f / (float)N;
    bf16x8 v = *(const bf16x8*)(z + i0);
    bf16x8 o;
#pragma unroll
    for (int u = 0; u < 8; ++u) {
        int cc = c + u;
        float m  = bns[cc] * invN;
        float va = bns[128 + cc] * invN - m * m;
        float iv = rsqrtf(va + 1e-5f);
        float sc = gamma[cc] * iv;
        float sh = beta[cc] - m * sc;
        o[u] = (bf16_t)fmaxf((float)v[u] * sc + sh, 0.f);
    }
    *(bf16x8*)(hbuf + i0) = o;
}

// ---------------------------------------------------------------------------
// FUSED aggregation + GINEConv MLP, 32-node tiles, 512-thread blocks.
// (Round-5 proven structure: byte-floor traffic, 63% occupancy, 80 us.)
// ---------------------------------------------------------------------------
__global__ __launch_bounds__(512, 8) void aggr_conv_kernel(
    const bf16_t* __restrict__ xin,
    const bf16_t* __restrict__ e,
    const int* __restrict__ rowptr, const int* __restrict__ srcp, int M,
    const bf16_t* __restrict__ Ws1, const float* __restrict__ b1,
    const bf16_t* __restrict__ Ws2, const float* __restrict__ b2,
    bf16_t* __restrict__ zout, float* __restrict__ bn_out)
{
    constexpr int S = 136;
    __shared__ bf16_t T[32 * S];
    __shared__ float  wred[2][256];

    const int  tid  = threadIdx.x;
    const int  wv   = tid >> 6, lane = tid & 63;
    const long row0 = (long)blockIdx.x * 32;
    const int  l16  = lane & 15, quad = lane >> 4;

    // preload this wave's 5 rowptr entries (rows nbase..nbase+4)
    const long nbase = row0 + wv * 4;
    int rpv = 0;
    {
        long idx = nbase + lane;
        if (idx > M) idx = M;
        if (lane <= 4) rpv = rowptr[idx];
    }

    // --- gather: 4 rows per wave, full wave per row, 2 cols/lane ---
#pragma unroll 1
    for (int ri = 0; ri < 4; ++ri) {
        const int  r   = wv * 4 + ri;
        const long n   = row0 + r;
        const int  beg = __shfl(rpv, ri);
        const int  end = __shfl(rpv, ri + 1);
        float ax = 0.f, ay = 0.f;
        if (n < M) {
            bf16x2 xv = *(const bf16x2*)(xin + n * 128 + lane * 2);
            ax = (float)xv[0]; ay = (float)xv[1];
            for (int base = beg; base < end; base += 64) {
                int cnt = min(64, end - base);
                int sv  = (base + lane < end) ? srcp[base + lane] : 0;
                int j = 0;
                for (; j + 3 < cnt; j += 4) {
                    int s0 = __shfl(sv, j),     s1 = __shfl(sv, j + 1);
                    int s2 = __shfl(sv, j + 2), s3 = __shfl(sv, j + 3);
                    bf16x2 x0 = *(const bf16x2*)(xin + (long)s0 * 128 + lane * 2);
                    bf16x2 x1 = *(const bf16x2*)(xin + (long)s1 * 128 + lane * 2);
                    bf16x2 x2 = *(const bf16x2*)(xin + (long)s2 * 128 + lane * 2);
                    bf16x2 x3 = *(const bf16x2*)(xin + (long)s3 * 128 + lane * 2);
                    bf16x2 e0 = *(const bf16x2*)(e + (long)(base + j + 0) * 128 + lane * 2);
                    bf16x2 e1 = *(const bf16x2*)(e + (long)(base + j + 1) * 128 + lane * 2);
                    bf16x2 e2 = *(const bf16x2*)(e + (long)(base + j + 2) * 128 + lane * 2);
                    bf16x2 e3 = *(const bf16x2*)(e + (long)(base + j + 3) * 128 + lane * 2);
                    ax += fmaxf((float)x0[0] + (float)e0[0], 0.f);
                    ay += fmaxf((float)x0[1] + (float)e0[1], 0.f);
                    ax += fmaxf((float)x1[0] + (float)e1[0], 0.f);
                    ay += fmaxf((float)x1[1] + (float)e1[1], 0.f);
                    ax += fmaxf((float)x2[0] + (float)e2[0], 0.f);
                    ay += fmaxf((float)x2[1] + (float)e2[1], 0.f);
                    ax += fmaxf((float)x3[0] + (float)e3[0], 0.f);
                    ay += fmaxf((float)x3[1] + (float)e3[1], 0.f);
                }
                for (; j < cnt; ++j) {
                    int s0 = __shfl(sv, j);
                    bf16x2 x0 = *(const bf16x2*)(xin + (long)s0 * 128 + lane * 2);
                    bf16x2 e0 = *(const bf16x2*)(e + (long)(base + j) * 128 + lane * 2);
                    ax += fmaxf((float)x0[0] + (float)e0[0], 0.f);
                    ay += fmaxf((float)x0[1] + (float)e0[1], 0.f);
                }
            }
        }
        bf16x2 o; o[0] = (bf16_t)ax; o[1] = (bf16_t)ay;
        *(bf16x2*)&T[r * S + lane * 2] = o;
    }
    __syncthreads();

    // --- MFMA: wave (rb, cq) owns rows rb*16..+16, c-tiles cq*2..cq*2+2 ---
    const int rb = wv >> 2, cq = wv & 3;
    const int mbase = rb * 16 + quad * 4;

    f32x4 acc[2];
#pragma unroll
    for (int c = 0; c < 2; c++) acc[c] = (f32x4){0.f, 0.f, 0.f, 0.f};

#pragma unroll
    for (int kc = 0; kc < 4; ++kc) {
        bf16x8 af = *(const bf16x8*)&T[(rb * 16 + l16) * S + kc * 32 + quad * 8];
#pragma unroll
        for (int c = 0; c < 2; c++) {
            int ct = cq * 2 + c;
            bf16x8 bfr = *(const bf16x8*)&Ws1[(((kc * 8 + ct) * 64) + lane) * 8];
            acc[c] = MFMA16(af, bfr, acc[c]);
        }
    }
    __syncthreads();   // done reading aggr tile

#pragma unroll
    for (int c = 0; c < 2; c++) {
        int col = (cq * 2 + c) * 16 + l16;
        float bb = b1[col];
#pragma unroll
        for (int q = 0; q < 4; q++)
            T[(mbase + q) * S + col] = (bf16_t)fmaxf(acc[c][q] + bb, 0.f);
    }
    __syncthreads();   // H complete

#pragma unroll
    for (int c = 0; c < 2; c++) acc[c] = (f32x4){0.f, 0.f, 0.f, 0.f};

#pragma unroll
    for (int kc = 0; kc < 4; ++kc) {
        bf16x8 af = *(const bf16x8*)&T[(rb * 16 + l16) * S + kc * 32 + quad * 8];
#pragma unroll
        for (int c = 0; c < 2; c++) {
            int ct = cq * 2 + c;
            bf16x8 bfr = *(const bf16x8*)&Ws2[(((kc * 8 + ct) * 64) + lane) * 8];
            acc[c] = MFMA16(af, bfr, acc[c]);
        }
    }
    __syncthreads();   // done reading H

    // Z epilogue: write Z to LDS, per-col stats into wred
#pragma unroll
    for (int c = 0; c < 2; c++) {
        int col = (cq * 2 + c) * 16 + l16;
        float bb = b2[col];
        float s = 0.f, s2 = 0.f;
#pragma unroll
        for (int q = 0; q < 4; q++) {
            float v = acc[c][q] + bb;
            T[(mbase + q) * S + col] = (bf16_t)v;
            if (row0 + mbase + q < M) { s += v; s2 += v * v; }
        }
        s  += __shfl_xor(s, 16);  s  += __shfl_xor(s, 32);
        s2 += __shfl_xor(s2, 16); s2 += __shfl_xor(s2, 32);
        if (quad == 0) {
            wred[rb][col]       = s;
            wred[rb][128 + col] = s2;
        }
    }
    __syncthreads();   // Z + wred complete

    // global Z write: 512 threads x 1 uint4 = 32 rows x 16 segs
    {
        int row = tid >> 4, seg = tid & 15;
        long grow = row0 + row;
        if (grow < M)
            *(uint4*)&zout[grow * 128 + seg * 8] = *(const uint4*)&T[row * S + seg * 8];
    }
    if (tid < 256) {
        float v = wred[0][tid] + wred[1][tid];
        atomicAdd(&bn_out[tid], v);
    }
}

// ---------------------------------------------------------------------------
// Mean-pool over sorted batch; derives final-layer BN inline.
// ---------------------------------------------------------------------------
__global__ __launch_bounds__(128) void pool_kernel(
    const bf16_t* __restrict__ z, const float* __restrict__ bns,
    const float* __restrict__ gamma, const float* __restrict__ beta,
    const int* __restrict__ batch,
    float* __restrict__ gsum, float* __restrict__ cnt, int N)
{
    int c = threadIdx.x;
    float mean = bns[c] / (float)N;
    float var  = bns[128 + c] / (float)N - mean * mean;
    float inv  = rsqrtf(var + 1e-5f);
    float sc   = gamma[c] * inv;
    float sh   = beta[c] - mean * sc;
    int n0 = blockIdx.x * 32;
    int n1 = min(n0 + 32, N);
    float acc = 0.f;
    int cur = -1, rc = 0;
    for (int n = n0; n < n1; ++n) {
        int g = batch[n];
        if (g != cur) {
            if (cur >= 0) {
                atomicAdd(&gsum[(long)cur * 128 + c], acc);
                if (c == 0) atomicAdd(&cnt[cur], (float)rc);
            }
            cur = g; acc = 0.f; rc = 0;
        }
        acc += fmaxf((float)z[(long)n * 128 + c] * sc + sh, 0.f);
        rc++;
    }
    if (cur >= 0) {
        atomicAdd(&gsum[(long)cur * 128 + c], acc);
        if (c == 0) atomicAdd(&cnt[cur], (float)rc);
    }
}

__global__ __launch_bounds__(128) void head_kernel(
    const float* __restrict__ gsum, const float* __restrict__ cnt,
    const float* __restrict__ ext_in,
    const float* __restrict__ ew1, const float* __restrict__ eb1,
    const float* __restrict__ ew2, const float* __restrict__ eb2,
    const float* __restrict__ rw1, const float* __restrict__ rb1,
    const float* __restrict__ rw2, const float* __restrict__ rb2,
    float* __restrict__ out)
{
    int g = blockIdx.x, c = threadIdx.x;
    __shared__ float sx[8];
    __shared__ float h1[128];
    __shared__ float comb[256];
    __shared__ float red[128];

    if (c < 8) sx[c] = ext_in[g * 8 + c];
    __syncthreads();
    float a = eb1[c];
#pragma unroll
    for (int k = 0; k < 8; k++) a += sx[k] * ew1[k * 128 + c];
    h1[c] = fmaxf(a, 0.f);
    __syncthreads();
    float b = eb2[c];
    for (int k = 0; k < 128; k++) b += h1[k] * ew2[k * 128 + c];
    comb[c]       = gsum[(long)g * 128 + c] / fmaxf(cnt[g], 1.0f);
    comb[128 + c] = b;
    __syncthreads();
    float r = rb1[c];
    for (int k = 0; k < 256; k++) r += comb[k] * rw1[k * 128 + c];
    r = fmaxf(r, 0.f);
    red[c] = r * rw2[c];
    __syncthreads();
    if (c == 0) {
        float s = rb2[0];
        for (int k = 0; k < 128; k++) s += red[k];
        out[g] = s;
    }
}

// ---------------------------------------------------------------------------
extern "C" void kernel_launch(void* const* d_in, const int* in_sizes, int n_in,
                              void* d_out, int out_size, void* d_ws, size_t ws_size,
                              hipStream_t stream)
{
    const float* x         = (const float*)d_in[0];
    const float* edge_attr = (const float*)d_in[1];
    const float* externals = (const float*)d_in[2];
    const float* node_w    = (const float*)d_in[3];
    const float* node_b    = (const float*)d_in[4];
    const float* ee_w1     = (const float*)d_in[5];
    const float* ee_b1     = (const float*)d_in[6];
    const float* ee_w2     = (const float*)d_in[7];
    const float* ee_b2     = (const float*)d_in[8];
    const float* conv_w1   = (const float*)d_in[9];
    const float* conv_b1   = (const float*)d_in[10];
    const float* conv_w2   = (const float*)d_in[11];
    const float* conv_b2   = (const float*)d_in[12];
    const float* bn_gamma  = (const float*)d_in[13];
    const float* bn_beta   = (const float*)d_in[14];
    const float* ext_w1    = (const float*)d_in[15];
    const float* ext_b1    = (const float*)d_in[16];
    const float* ext_w2    = (const float*)d_in[17];
    const float* ext_b2    = (const float*)d_in[18];
    const float* reg_w1    = (const float*)d_in[19];
    const float* reg_b1    = (const float*)d_in[20];
    const float* reg_w2    = (const float*)d_in[21];
    const float* reg_b2    = (const float*)d_in[22];
    const int* edge_index  = (const int*)d_in[23];
    const int* batch       = (const int*)d_in[24];

    const int N = in_sizes[0] / 32;
    const int E = in_sizes[1] / 16;
    const int G = in_sizes[2] / 8;
    const int NB = (N + 1023) / 1024;

    char* p = (char*)d_ws;
    auto alloc = [&](size_t bytes) -> void* {
        void* r = (void*)p;
        p += (bytes + 255) & ~(size_t)255;
        return r;
    };
    bf16_t* h       = (bf16_t*)alloc((size_t)N * 128 * 2);
    bf16_t* zA      = (bf16_t*)alloc((size_t)N * 128 * 2);
    bf16_t* zB      = (bf16_t*)alloc((size_t)N * 128 * 2);
    bf16_t* hb      = (bf16_t*)alloc((size_t)N * 128 * 2);   // BN-activated nodes
    bf16_t* ebuf    = (bf16_t*)alloc((size_t)E * 128 * 2);   // dst-sorted
    int*    deg     = (int*)alloc((size_t)N * 4);
    int*    rowptr  = (int*)alloc(((size_t)N + 1) * 4);
    int*    cursor  = (int*)alloc((size_t)N * 4);
    int*    partials= (int*)alloc((size_t)N * 4);
    int*    bsums   = (int*)alloc((size_t)NB * 4);
    int*    boff    = (int*)alloc((size_t)NB * 4);
    int*    srcp    = (int*)alloc((size_t)E * 4);
    int*    epos    = (int*)alloc((size_t)E * 4);
    bf16_t* node_wt = (bf16_t*)alloc(128 * 32 * 2);
    bf16_t* ee_w1t  = (bf16_t*)alloc(128 * 32 * 2);
    bf16_t* ee_w2t  = (bf16_t*)alloc(128 * 128 * 2);
    bf16_t* cw1t    = (bf16_t*)alloc(3 * 128 * 128 * 2);
    bf16_t* cw2t    = (bf16_t*)alloc(3 * 128 * 128 * 2);
    float*  bns     = (float*)alloc(3 * 256 * 4);            // per-layer BN sums
    float*  gsum    = (float*)alloc((size_t)G * 128 * 4);
    float*  cnt     = (float*)alloc((size_t)G * 4);

    // --- CSR build (by dst); hist also warms edge_attr into MALL ---
    hipMemsetAsync(deg, 0, (size_t)N * 4, stream);
    hipMemsetAsync(bns, 0, 3 * 256 * 4, stream);
    hist_kernel<<<(E + 255) / 256, 256, 0, stream>>>(edge_index, deg, E, edge_attr);
    scanA_kernel<<<NB, 256, 0, stream>>>(deg, partials, bsums, N);
    scanB_kernel<<<1, 256, 0, stream>>>(bsums, boff, rowptr, NB, N);
    scanC_kernel<<<(N + 255) / 256, 256, 0, stream>>>(partials, boff, rowptr, cursor, N);
    scatter_kernel<<<(E + 255) / 256, 256, 0, stream>>>(edge_index, cursor, srcp, epos, E);

    // --- weight prep (single launch) ---
    prep_all_kernel<<<480, 256, 0, stream>>>(node_w, ee_w1, ee_w2, conv_w1, conv_w2,
                                             node_wt, ee_w1t, ee_w2t, cw1t, cw2t);

    // --- node encoder ---
    node_enc_kernel<<<(N + 127) / 128, 256, 0, stream>>>(x, N, node_wt, node_b, h);

    // --- edge encoder: sequential read, scatter write to CSR slots ---
    edge_mlp_kernel<<<(E + 63) / 64, 256, 0, stream>>>(
        edge_attr, E, ee_w1t, ee_b1, ee_w2t, ee_b2, epos, ebuf);

    // --- GINE layers (activation pre-materialized via bnx) ---
    const int nblk = (N + 31) / 32;
    const int bblk = ((N * 128 / 8) + 255) / 256;
    aggr_conv_kernel<<<nblk, 512, 0, stream>>>(
        h, ebuf, rowptr, srcp, N,
        cw1t + 0 * 16384, conv_b1 + 0 * 128, cw2t + 0 * 16384, conv_b2 + 0 * 128,
        zA, bns + 0);
    bnx_kernel<<<bblk, 256, 0, stream>>>(zA, bns + 0, bn_gamma + 0, bn_beta + 0, hb, N);
    aggr_conv_kernel<<<nblk, 512, 0, stream>>>(
        hb, ebuf, rowptr, srcp, N,
        cw1t + 1 * 16384, conv_b1 + 1 * 128, cw2t + 1 * 16384, conv_b2 + 1 * 128,
        zB, bns + 256);
    bnx_kernel<<<bblk, 256, 0, stream>>>(zB, bns + 256, bn_gamma + 128, bn_beta + 128, hb, N);
    aggr_conv_kernel<<<nblk, 512, 0, stream>>>(
        hb, ebuf, rowptr, srcp, N,
        cw1t + 2 * 16384, conv_b1 + 2 * 128, cw2t + 2 * 16384, conv_b2 + 2 * 128,
        zA, bns + 512);

    // --- pooling (BN+relu applied on read) + head ---
    hipMemsetAsync(gsum, 0, (size_t)G * 128 * 4, stream);
    hipMemsetAsync(cnt, 0, (size_t)G * 4, stream);
    pool_kernel<<<(N + 31) / 32, 128, 0, stream>>>(zA, bns + 512, bn_gamma + 256, bn_beta + 256,
                                                   batch, gsum, cnt, N);
    head_kernel<<<G, 128, 0, stream>>>(gsum, cnt, externals,
                                       ext_w1, ext_b1, ext_w2, ext_b2,
                                       reg_w1, reg_b1, reg_w2, reg_b2,
                                       (float*)d_out);
}

// Round 8
// 544.681 us; speedup vs baseline: 1.3729x; 1.0088x over previous
//
#include <hip/hip_runtime.h>

typedef __bf16 bf16_t;
typedef __bf16 bf16x8 __attribute__((ext_vector_type(8)));
typedef __bf16 bf16x4 __attribute__((ext_vector_type(4)));
typedef __bf16 bf16x2 __attribute__((ext_vector_type(2)));
typedef float  f32x4  __attribute__((ext_vector_type(4)));

#define MFMA16(a, b, c) __builtin_amdgcn_mfma_f32_16x16x32_bf16((a), (b), (c), 0, 0, 0)

// ---------------------------------------------------------------------------
// Fused weight prep: all 8 matrices in one launch.
// ---------------------------------------------------------------------------
__global__ __launch_bounds__(256) void prep_all_kernel(
    const float* __restrict__ nw,  const float* __restrict__ ew1,
    const float* __restrict__ ew2, const float* __restrict__ cw1,
    const float* __restrict__ cw2,
    bf16_t* __restrict__ nwt,  bf16_t* __restrict__ ew1t,
    bf16_t* __restrict__ ew2t, bf16_t* __restrict__ cw1t,
    bf16_t* __restrict__ cw2t)
{
    int b = blockIdx.x;
    const float* W; bf16_t* O; int Kact, KP, lb;
    if (b < 16)       { W = nw;  O = nwt;  Kact = 32;  KP = 32;  lb = b; }
    else if (b < 32)  { W = ew1; O = ew1t; Kact = 16;  KP = 32;  lb = b - 16; }
    else if (b < 96)  { W = ew2; O = ew2t; Kact = 128; KP = 128; lb = b - 32; }
    else if (b < 288) { int l = (b - 96) / 64;  W = cw1 + l * 16384; O = cw1t + l * 16384;
                        Kact = 128; KP = 128; lb = (b - 96) % 64; }
    else              { int l = (b - 288) / 64; W = cw2 + l * 16384; O = cw2t + l * 16384;
                        Kact = 128; KP = 128; lb = (b - 288) % 64; }
    int idx = lb * 256 + threadIdx.x;
    if (idx >= 128 * KP) return;
    int j    = idx & 7;
    int lane = (idx >> 3) & 63;
    int ct   = (idx >> 9) & 7;
    int kc   = idx >> 12;
    int n = ct * 16 + (lane & 15);
    int k = kc * 32 + (lane >> 4) * 8 + j;
    O[idx] = (bf16_t)((k < Kact) ? W[k * 128 + n] : 0.0f);
}

// ---------------------------------------------------------------------------
// CSR build; hist also warms edge_attr into the MALL.
// ---------------------------------------------------------------------------
__global__ __launch_bounds__(256) void hist_kernel(const int* __restrict__ ei,
                                                   int* __restrict__ deg, int E,
                                                   const float* __restrict__ ea) {
    int t = blockIdx.x * 256 + threadIdx.x;
    if (t < E) {
        atomicAdd(&deg[ei[(long)E + t]], 1);
        float w0 = ea[(long)t * 16];
        float w1 = ea[(long)t * 16 + 8];
        asm volatile("" :: "v"(w0), "v"(w1));
    }
}

__global__ __launch_bounds__(256) void scanA_kernel(const int* __restrict__ deg,
                                                    int* __restrict__ partials,
                                                    int* __restrict__ bsums, int N) {
    __shared__ int s[256];
    int b = blockIdx.x, t = threadIdx.x;
    int base = b * 1024 + t * 4;
    int v0 = (base + 0 < N) ? deg[base + 0] : 0;
    int v1 = (base + 1 < N) ? deg[base + 1] : 0;
    int v2 = (base + 2 < N) ? deg[base + 2] : 0;
    int v3 = (base + 3 < N) ? deg[base + 3] : 0;
    int local = v0 + v1 + v2 + v3;
    s[t] = local;
    __syncthreads();
    for (int off = 1; off < 256; off <<= 1) {
        int v = (t >= off) ? s[t - off] : 0;
        __syncthreads();
        s[t] += v;
        __syncthreads();
    }
    int excl = s[t] - local;
    if (base + 0 < N) partials[base + 0] = excl;
    if (base + 1 < N) partials[base + 1] = excl + v0;
    if (base + 2 < N) partials[base + 2] = excl + v0 + v1;
    if (base + 3 < N) partials[base + 3] = excl + v0 + v1 + v2;
    if (t == 255) bsums[b] = s[255];
}

__global__ __launch_bounds__(256) void scanB_kernel(const int* __restrict__ bsums,
                                                    int* __restrict__ boff,
                                                    int* __restrict__ rowptr,
                                                    int NB, int N) {
    __shared__ int s[256];
    int t = threadIdx.x;
    int local = (t < NB) ? bsums[t] : 0;
    s[t] = local;
    __syncthreads();
    for (int off = 1; off < 256; off <<= 1) {
        int v = (t >= off) ? s[t - off] : 0;
        __syncthreads();
        s[t] += v;
        __syncthreads();
    }
    if (t < NB) boff[t] = s[t] - local;
    if (t == NB - 1) rowptr[N] = s[t];
}

__global__ __launch_bounds__(256) void scanC_kernel(const int* __restrict__ partials,
                                                    const int* __restrict__ boff,
                                                    int* __restrict__ rowptr,
                                                    int* __restrict__ cursor, int N) {
    int i = blockIdx.x * 256 + threadIdx.x;
    if (i >= N) return;
    int v = partials[i] + boff[i >> 10];
    rowptr[i] = v;
    cursor[i] = v;
}

// scatter also records epos[t] = CSR slot of original edge t
__global__ __launch_bounds__(256) void scatter_kernel(const int* __restrict__ ei,
                                                      int* __restrict__ cursor,
                                                      int* __restrict__ srcp,
                                                      int* __restrict__ epos, int E) {
    int t = blockIdx.x * 256 + threadIdx.x;
    if (t >= E) return;
    int d = ei[(long)E + t];
    int pos = atomicAdd(&cursor[d], 1);
    srcp[pos] = ei[t];
    epos[t] = pos;
}

// ---------------------------------------------------------------------------
// Node encoder: h = x[M,32] @ W + bias, out bf16. Barrier-free wave-private.
// ---------------------------------------------------------------------------
__global__ __launch_bounds__(256) void node_enc_kernel(
    const float* __restrict__ A, int M,
    const bf16_t* __restrict__ Ws, const float* __restrict__ bias,
    bf16_t* __restrict__ outp)
{
    constexpr int S = 136;
    __shared__ bf16_t T[128 * S];

    const int  tid  = threadIdx.x;
    const int  wv   = tid >> 6, lane = tid & 63;
    const long row0 = (long)blockIdx.x * 128;
    const int  l16  = lane & 15, quad = lane >> 4;

    {
        int r  = wv * 32 + (lane >> 1);
        long gr = row0 + r;
        int c0 = (lane & 1) * 16;
#pragma unroll
        for (int q = 0; q < 4; ++q) {
            float4 v = make_float4(0.f, 0.f, 0.f, 0.f);
            if (gr < M) v = *(const float4*)(A + gr * 32 + c0 + q * 4);
            bf16_t* d = &T[r * S + c0 + q * 4];
            d[0] = (bf16_t)v.x; d[1] = (bf16_t)v.y; d[2] = (bf16_t)v.z; d[3] = (bf16_t)v.w;
        }
    }

    f32x4 acc[2][8];
#pragma unroll
    for (int r = 0; r < 2; r++)
#pragma unroll
        for (int c = 0; c < 8; c++) acc[r][c] = (f32x4){0.f, 0.f, 0.f, 0.f};

    {
        bf16x8 af0 = *(const bf16x8*)&T[(wv * 32 + l16) * S + quad * 8];
        bf16x8 af1 = *(const bf16x8*)&T[(wv * 32 + 16 + l16) * S + quad * 8];
#pragma unroll
        for (int c = 0; c < 8; c++) {
            bf16x8 bfr = *(const bf16x8*)&Ws[((c * 64) + lane) * 8];
            acc[0][c] = MFMA16(af0, bfr, acc[0][c]);
            acc[1][c] = MFMA16(af1, bfr, acc[1][c]);
        }
    }

#pragma unroll
    for (int r = 0; r < 2; r++) {
        int mrow = wv * 32 + r * 16 + quad * 4;
#pragma unroll
        for (int c = 0; c < 8; c++) {
            int col = c * 16 + l16;
            float bb = bias[col];
#pragma unroll
            for (int q = 0; q < 4; q++)
                T[(mrow + q) * S + col] = (bf16_t)(acc[r][c][q] + bb);
        }
    }

#pragma unroll
    for (int it = 0; it < 8; ++it) {
        int idx = it * 64 + lane;
        int row = wv * 32 + (idx >> 4);
        int seg = idx & 15;
        long grow = row0 + row;
        if (grow < M)
            *(uint4*)&outp[grow * 128 + seg * 8] = *(const uint4*)&T[row * S + seg * 8];
    }
}

// ---------------------------------------------------------------------------
// Fused edge encoder, 64-row tiles: sequential read, scatter-write to CSR.
// ---------------------------------------------------------------------------
__global__ __launch_bounds__(256) void edge_mlp_kernel(
    const float* __restrict__ A, int M,
    const bf16_t* __restrict__ Ws1, const float* __restrict__ b1,
    const bf16_t* __restrict__ Ws2, const float* __restrict__ b2,
    const int* __restrict__ epos, bf16_t* __restrict__ outp)
{
    constexpr int S = 136;
    __shared__ bf16_t T[64 * S];

    const int  tid  = threadIdx.x;
    const int  wv   = tid >> 6, lane = tid & 63;
    const long row0 = (long)blockIdx.x * 64;
    const int  l16  = lane & 15, quad = lane >> 4;

    {   // sequential coalesced load: 4 lanes per row, one float4 per lane
        int  r  = wv * 16 + (lane >> 2);
        long gr = row0 + r;
        float4 v = make_float4(0.f, 0.f, 0.f, 0.f);
        if (gr < M) v = *(const float4*)(A + gr * 16 + (lane & 3) * 4);
        bf16_t* d = &T[r * S + (lane & 3) * 4];
        d[0] = (bf16_t)v.x; d[1] = (bf16_t)v.y; d[2] = (bf16_t)v.z; d[3] = (bf16_t)v.w;
    }

    f32x4 acc[8];
#pragma unroll
    for (int c = 0; c < 8; c++) acc[c] = (f32x4){0.f, 0.f, 0.f, 0.f};

    {   // stage 1: K=16
        bf16x8 af;
#pragma unroll
        for (int j = 0; j < 8; ++j) af[j] = (bf16_t)0.f;
        if (quad < 2) af = *(const bf16x8*)&T[(wv * 16 + l16) * S + quad * 8];
#pragma unroll
        for (int c = 0; c < 8; c++) {
            bf16x8 bfr = *(const bf16x8*)&Ws1[((c * 64) + lane) * 8];
            acc[c] = MFMA16(af, bfr, acc[c]);
        }
    }

    const int mbase = wv * 16 + quad * 4;

#pragma unroll
    for (int c = 0; c < 8; c++) {
        int col = c * 16 + l16;
        float bb = b1[col];
#pragma unroll
        for (int q = 0; q < 4; q++)
            T[(mbase + q) * S + col] = (bf16_t)fmaxf(acc[c][q] + bb, 0.f);
    }

#pragma unroll
    for (int c = 0; c < 8; c++) acc[c] = (f32x4){0.f, 0.f, 0.f, 0.f};

#pragma unroll
    for (int kc = 0; kc < 4; ++kc) {   // stage 2: K=128
        bf16x8 af = *(const bf16x8*)&T[(wv * 16 + l16) * S + kc * 32 + quad * 8];
#pragma unroll
        for (int c = 0; c < 8; c++) {
            bf16x8 bfr = *(const bf16x8*)&Ws2[(((kc * 8 + c) * 64) + lane) * 8];
            acc[c] = MFMA16(af, bfr, acc[c]);
        }
    }

#pragma unroll
    for (int c = 0; c < 8; c++) {
        int col = c * 16 + l16;
        float bb = b2[col];
#pragma unroll
        for (int q = 0; q < 4; q++)
            T[(mbase + q) * S + col] = (bf16_t)(acc[c][q] + bb);
    }

    // scatter store: own 16 rows, 4 uint4 per lane, to CSR slots
#pragma unroll
    for (int it = 0; it < 4; ++it) {
        int idx = it * 64 + lane;
        int row = wv * 16 + (idx >> 4);
        int seg = idx & 15;
        long grow = row0 + row;
        if (grow < M) {
            long pos = epos[grow];
            *(uint4*)&outp[pos * 128 + seg * 8] = *(const uint4*)&T[row * S + seg * 8];
        }
    }
}

// ---------------------------------------------------------------------------
// BN+relu materialization: hbuf = relu(z*sc+sh), bf16x8 per thread.
// ---------------------------------------------------------------------------
__global__ __launch_bounds__(256) void bnx_kernel(
    const bf16_t* __restrict__ z, const float* __restrict__ bns,
    const float* __restrict__ gamma, const float* __restrict__ beta,
    bf16_t* __restrict__ hbuf, int N)
{
    long t = (long)blockIdx.x * 256 + threadIdx.x;
    long i0 = t * 8;
    if (i0 >= (long)N * 128) return;
    int c = (int)(i0 & 127);
    const float invN = 1.f / (float)N;
    bf16x8 v = *(const bf16x8*)(z + i0);
    bf16x8 o;
#pragma unroll
    for (int u = 0; u < 8; ++u) {
        int cc = c + u;
        float m  = bns[cc] * invN;
        float va = bns[128 + cc] * invN - m * m;
        float iv = rsqrtf(va + 1e-5f);
        float sc = gamma[cc] * iv;
        float sh = beta[cc] - m * sc;
        o[u] = (bf16_t)fmaxf((float)v[u] * sc + sh, 0.f);
    }
    *(bf16x8*)(hbuf + i0) = o;
}

// ---------------------------------------------------------------------------
// FUSED aggregation + GINEConv MLP, 32-node tiles, 512-thread blocks.
// Round-7 structure + TWO isolated read-side tweaks:
//   (1) 8-edge inner batches -> 16 outstanding loads/wave (2x in-flight
//       bytes; we sit at the latency*BW concurrency knee),
//   (2) non-temporal loads on ebuf (read-exactly-once; stop evicting the
//       13x-reused x rows from L2).
// ---------------------------------------------------------------------------
__global__ __launch_bounds__(512, 8) void aggr_conv_kernel(
    const bf16_t* __restrict__ xin,
    const bf16_t* __restrict__ e,
    const int* __restrict__ rowptr, const int* __restrict__ srcp, int M,
    const bf16_t* __restrict__ Ws1, const float* __restrict__ b1,
    const bf16_t* __restrict__ Ws2, const float* __restrict__ b2,
    bf16_t* __restrict__ zout, float* __restrict__ bn_out)
{
    constexpr int S = 136;
    __shared__ bf16_t T[32 * S];
    __shared__ float  wred[2][256];

    const int  tid  = threadIdx.x;
    const int  wv   = tid >> 6, lane = tid & 63;
    const long row0 = (long)blockIdx.x * 32;
    const int  l16  = lane & 15, quad = lane >> 4;

    // preload this wave's 5 rowptr entries (rows nbase..nbase+4)
    const long nbase = row0 + wv * 4;
    int rpv = 0;
    {
        long idx = nbase + lane;
        if (idx > M) idx = M;
        if (lane <= 4) rpv = rowptr[idx];
    }

    // --- gather: 4 rows per wave, full wave per row, 2 cols/lane ---
#pragma unroll 1
    for (int ri = 0; ri < 4; ++ri) {
        const int  r   = wv * 4 + ri;
        const long n   = row0 + r;
        const int  beg = __shfl(rpv, ri);
        const int  end = __shfl(rpv, ri + 1);
        float ax = 0.f, ay = 0.f;
        if (n < M) {
            bf16x2 xv = *(const bf16x2*)(xin + n * 128 + lane * 2);
            ax = (float)xv[0]; ay = (float)xv[1];
            for (int base = beg; base < end; base += 64) {
                int cnt = min(64, end - base);
                int sv  = (base + lane < end) ? srcp[base + lane] : 0;
                int j = 0;
                for (; j + 7 < cnt; j += 8) {   // 16 loads in flight
                    int s0 = __shfl(sv, j),     s1 = __shfl(sv, j + 1);
                    int s2 = __shfl(sv, j + 2), s3 = __shfl(sv, j + 3);
                    int s4 = __shfl(sv, j + 4), s5 = __shfl(sv, j + 5);
                    int s6 = __shfl(sv, j + 6), s7 = __shfl(sv, j + 7);
                    bf16x2 x0 = *(const bf16x2*)(xin + (long)s0 * 128 + lane * 2);
                    bf16x2 x1 = *(const bf16x2*)(xin + (long)s1 * 128 + lane * 2);
                    bf16x2 x2 = *(const bf16x2*)(xin + (long)s2 * 128 + lane * 2);
                    bf16x2 x3 = *(const bf16x2*)(xin + (long)s3 * 128 + lane * 2);
                    bf16x2 x4 = *(const bf16x2*)(xin + (long)s4 * 128 + lane * 2);
                    bf16x2 x5 = *(const bf16x2*)(xin + (long)s5 * 128 + lane * 2);
                    bf16x2 x6 = *(const bf16x2*)(xin + (long)s6 * 128 + lane * 2);
                    bf16x2 x7 = *(const bf16x2*)(xin + (long)s7 * 128 + lane * 2);
                    bf16x2 e0 = __builtin_nontemporal_load((const bf16x2*)(e + (long)(base + j + 0) * 128 + lane * 2));
                    bf16x2 e1 = __builtin_nontemporal_load((const bf16x2*)(e + (long)(base + j + 1) * 128 + lane * 2));
                    bf16x2 e2 = __builtin_nontemporal_load((const bf16x2*)(e + (long)(base + j + 2) * 128 + lane * 2));
                    bf16x2 e3 = __builtin_nontemporal_load((const bf16x2*)(e + (long)(base + j + 3) * 128 + lane * 2));
                    bf16x2 e4 = __builtin_nontemporal_load((const bf16x2*)(e + (long)(base + j + 4) * 128 + lane * 2));
                    bf16x2 e5 = __builtin_nontemporal_load((const bf16x2*)(e + (long)(base + j + 5) * 128 + lane * 2));
                    bf16x2 e6 = __builtin_nontemporal_load((const bf16x2*)(e + (long)(base + j + 6) * 128 + lane * 2));
                    bf16x2 e7 = __builtin_nontemporal_load((const bf16x2*)(e + (long)(base + j + 7) * 128 + lane * 2));
                    ax += fmaxf((float)x0[0] + (float)e0[0], 0.f);
                    ay += fmaxf((float)x0[1] + (float)e0[1], 0.f);
                    ax += fmaxf((float)x1[0] + (float)e1[0], 0.f);
                    ay += fmaxf((float)x1[1] + (float)e1[1], 0.f);
                    ax += fmaxf((float)x2[0] + (float)e2[0], 0.f);
                    ay += fmaxf((float)x2[1] + (float)e2[1], 0.f);
                    ax += fmaxf((float)x3[0] + (float)e3[0], 0.f);
                    ay += fmaxf((float)x3[1] + (float)e3[1], 0.f);
                    ax += fmaxf((float)x4[0] + (float)e4[0], 0.f);
                    ay += fmaxf((float)x4[1] + (float)e4[1], 0.f);
                    ax += fmaxf((float)x5[0] + (float)e5[0], 0.f);
                    ay += fmaxf((float)x5[1] + (float)e5[1], 0.f);
                    ax += fmaxf((float)x6[0] + (float)e6[0], 0.f);
                    ay += fmaxf((float)x6[1] + (float)e6[1], 0.f);
                    ax += fmaxf((float)x7[0] + (float)e7[0], 0.f);
                    ay += fmaxf((float)x7[1] + (float)e7[1], 0.f);
                }
                for (; j + 3 < cnt; j += 4) {
                    int s0 = __shfl(sv, j),     s1 = __shfl(sv, j + 1);
                    int s2 = __shfl(sv, j + 2), s3 = __shfl(sv, j + 3);
                    bf16x2 x0 = *(const bf16x2*)(xin + (long)s0 * 128 + lane * 2);
                    bf16x2 x1 = *(const bf16x2*)(xin + (long)s1 * 128 + lane * 2);
                    bf16x2 x2 = *(const bf16x2*)(xin + (long)s2 * 128 + lane * 2);
                    bf16x2 x3 = *(const bf16x2*)(xin + (long)s3 * 128 + lane * 2);
                    bf16x2 e0 = __builtin_nontemporal_load((const bf16x2*)(e + (long)(base + j + 0) * 128 + lane * 2));
                    bf16x2 e1 = __builtin_nontemporal_load((const bf16x2*)(e + (long)(base + j + 1) * 128 + lane * 2));
                    bf16x2 e2 = __builtin_nontemporal_load((const bf16x2*)(e + (long)(base + j + 2) * 128 + lane * 2));
                    bf16x2 e3 = __builtin_nontemporal_load((const bf16x2*)(e + (long)(base + j + 3) * 128 + lane * 2));
                    ax += fmaxf((float)x0[0] + (float)e0[0], 0.f);
                    ay += fmaxf((float)x0[1] + (float)e0[1], 0.f);
                    ax += fmaxf((float)x1[0] + (float)e1[0], 0.f);
                    ay += fmaxf((float)x1[1] + (float)e1[1], 0.f);
                    ax += fmaxf((float)x2[0] + (float)e2[0], 0.f);
                    ay += fmaxf((float)x2[1] + (float)e2[1], 0.f);
                    ax += fmaxf((float)x3[0] + (float)e3[0], 0.f);
                    ay += fmaxf((float)x3[1] + (float)e3[1], 0.f);
                }
                for (; j < cnt; ++j) {
                    int s0 = __shfl(sv, j);
                    bf16x2 x0 = *(const bf16x2*)(xin + (long)s0 * 128 + lane * 2);
                    bf16x2 e0 = __builtin_nontemporal_load((const bf16x2*)(e + (long)(base + j) * 128 + lane * 2));
                    ax += fmaxf((float)x0[0] + (float)e0[0], 0.f);
                    ay += fmaxf((float)x0[1] + (float)e0[1], 0.f);
                }
            }
        }
        bf16x2 o; o[0] = (bf16_t)ax; o[1] = (bf16_t)ay;
        *(bf16x2*)&T[r * S + lane * 2] = o;
    }
    __syncthreads();

    // --- MFMA: wave (rb, cq) owns rows rb*16..+16, c-tiles cq*2..cq*2+2 ---
    const int rb = wv >> 2, cq = wv & 3;
    const int mbase = rb * 16 + quad * 4;

    f32x4 acc[2];
#pragma unroll
    for (int c = 0; c < 2; c++) acc[c] = (f32x4){0.f, 0.f, 0.f, 0.f};

#pragma unroll
    for (int kc = 0; kc < 4; ++kc) {
        bf16x8 af = *(const bf16x8*)&T[(rb * 16 + l16) * S + kc * 32 + quad * 8];
#pragma unroll
        for (int c = 0; c < 2; c++) {
            int ct = cq * 2 + c;
            bf16x8 bfr = *(const bf16x8*)&Ws1[(((kc * 8 + ct) * 64) + lane) * 8];
            acc[c] = MFMA16(af, bfr, acc[c]);
        }
    }
    __syncthreads();   // done reading aggr tile

#pragma unroll
    for (int c = 0; c < 2; c++) {
        int col = (cq * 2 + c) * 16 + l16;
        float bb = b1[col];
#pragma unroll
        for (int q = 0; q < 4; q++)
            T[(mbase + q) * S + col] = (bf16_t)fmaxf(acc[c][q] + bb, 0.f);
    }
    __syncthreads();   // H complete

#pragma unroll
    for (int c = 0; c < 2; c++) acc[c] = (f32x4){0.f, 0.f, 0.f, 0.f};

#pragma unroll
    for (int kc = 0; kc < 4; ++kc) {
        bf16x8 af = *(const bf16x8*)&T[(rb * 16 + l16) * S + kc * 32 + quad * 8];
#pragma unroll
        for (int c = 0; c < 2; c++) {
            int ct = cq * 2 + c;
            bf16x8 bfr = *(const bf16x8*)&Ws2[(((kc * 8 + ct) * 64) + lane) * 8];
            acc[c] = MFMA16(af, bfr, acc[c]);
        }
    }
    __syncthreads();   // done reading H

    // Z epilogue: write Z to LDS, per-col stats into wred
#pragma unroll
    for (int c = 0; c < 2; c++) {
        int col = (cq * 2 + c) * 16 + l16;
        float bb = b2[col];
        float s = 0.f, s2 = 0.f;
#pragma unroll
        for (int q = 0; q < 4; q++) {
            float v = acc[c][q] + bb;
            T[(mbase + q) * S + col] = (bf16_t)v;
            if (row0 + mbase + q < M) { s += v; s2 += v * v; }
        }
        s  += __shfl_xor(s, 16);  s  += __shfl_xor(s, 32);
        s2 += __shfl_xor(s2, 16); s2 += __shfl_xor(s2, 32);
        if (quad == 0) {
            wred[rb][col]       = s;
            wred[rb][128 + col] = s2;
        }
    }
    __syncthreads();   // Z + wred complete

    // global Z write: 512 threads x 1 uint4 = 32 rows x 16 segs
    {
        int row = tid >> 4, seg = tid & 15;
        long grow = row0 + row;
        if (grow < M)
            *(uint4*)&zout[grow * 128 + seg * 8] = *(const uint4*)&T[row * S + seg * 8];
    }
    if (tid < 256) {
        float v = wred[0][tid] + wred[1][tid];
        atomicAdd(&bn_out[tid], v);
    }
}

// ---------------------------------------------------------------------------
// Mean-pool over sorted batch; derives final-layer BN inline.
// ---------------------------------------------------------------------------
__global__ __launch_bounds__(128) void pool_kernel(
    const bf16_t* __restrict__ z, const float* __restrict__ bns,
    const float* __restrict__ gamma, const float* __restrict__ beta,
    const int* __restrict__ batch,
    float* __restrict__ gsum, float* __restrict__ cnt, int N)
{
    int c = threadIdx.x;
    float mean = bns[c] / (float)N;
    float var  = bns[128 + c] / (float)N - mean * mean;
    float inv  = rsqrtf(var + 1e-5f);
    float sc   = gamma[c] * inv;
    float sh   = beta[c] - mean * sc;
    int n0 = blockIdx.x * 32;
    int n1 = min(n0 + 32, N);
    float acc = 0.f;
    int cur = -1, rc = 0;
    for (int n = n0; n < n1; ++n) {
        int g = batch[n];
        if (g != cur) {
            if (cur >= 0) {
                atomicAdd(&gsum[(long)cur * 128 + c], acc);
                if (c == 0) atomicAdd(&cnt[cur], (float)rc);
            }
            cur = g; acc = 0.f; rc = 0;
        }
        acc += fmaxf((float)z[(long)n * 128 + c] * sc + sh, 0.f);
        rc++;
    }
    if (cur >= 0) {
        atomicAdd(&gsum[(long)cur * 128 + c], acc);
        if (c == 0) atomicAdd(&cnt[cur], (float)rc);
    }
}

__global__ __launch_bounds__(128) void head_kernel(
    const float* __restrict__ gsum, const float* __restrict__ cnt,
    const float* __restrict__ ext_in,
    const float* __restrict__ ew1, const float* __restrict__ eb1,
    const float* __restrict__ ew2, const float* __restrict__ eb2,
    const float* __restrict__ rw1, const float* __restrict__ rb1,
    const float* __restrict__ rw2, const float* __restrict__ rb2,
    float* __restrict__ out)
{
    int g = blockIdx.x, c = threadIdx.x;
    __shared__ float sx[8];
    __shared__ float h1[128];
    __shared__ float comb[256];
    __shared__ float red[128];

    if (c < 8) sx[c] = ext_in[g * 8 + c];
    __syncthreads();
    float a = eb1[c];
#pragma unroll
    for (int k = 0; k < 8; k++) a += sx[k] * ew1[k * 128 + c];
    h1[c] = fmaxf(a, 0.f);
    __syncthreads();
    float b = eb2[c];
    for (int k = 0; k < 128; k++) b += h1[k] * ew2[k * 128 + c];
    comb[c]       = gsum[(long)g * 128 + c] / fmaxf(cnt[g], 1.0f);
    comb[128 + c] = b;
    __syncthreads();
    float r = rb1[c];
    for (int k = 0; k < 256; k++) r += comb[k] * rw1[k * 128 + c];
    r = fmaxf(r, 0.f);
    red[c] = r * rw2[c];
    __syncthreads();
    if (c == 0) {
        float s = rb2[0];
        for (int k = 0; k < 128; k++) s += red[k];
        out[g] = s;
    }
}

// ---------------------------------------------------------------------------
extern "C" void kernel_launch(void* const* d_in, const int* in_sizes, int n_in,
                              void* d_out, int out_size, void* d_ws, size_t ws_size,
                              hipStream_t stream)
{
    const float* x         = (const float*)d_in[0];
    const float* edge_attr = (const float*)d_in[1];
    const float* externals = (const float*)d_in[2];
    const float* node_w    = (const float*)d_in[3];
    const float* node_b    = (const float*)d_in[4];
    const float* ee_w1     = (const float*)d_in[5];
    const float* ee_b1     = (const float*)d_in[6];
    const float* ee_w2     = (const float*)d_in[7];
    const float* ee_b2     = (const float*)d_in[8];
    const float* conv_w1   = (const float*)d_in[9];
    const float* conv_b1   = (const float*)d_in[10];
    const float* conv_w2   = (const float*)d_in[11];
    const float* conv_b2   = (const float*)d_in[12];
    const float* bn_gamma  = (const float*)d_in[13];
    const float* bn_beta   = (const float*)d_in[14];
    const float* ext_w1    = (const float*)d_in[15];
    const float* ext_b1    = (const float*)d_in[16];
    const float* ext_w2    = (const float*)d_in[17];
    const float* ext_b2    = (const float*)d_in[18];
    const float* reg_w1    = (const float*)d_in[19];
    const float* reg_b1    = (const float*)d_in[20];
    const float* reg_w2    = (const float*)d_in[21];
    const float* reg_b2    = (const float*)d_in[22];
    const int* edge_index  = (const int*)d_in[23];
    const int* batch       = (const int*)d_in[24];

    const int N = in_sizes[0] / 32;
    const int E = in_sizes[1] / 16;
    const int G = in_sizes[2] / 8;
    const int NB = (N + 1023) / 1024;

    char* p = (char*)d_ws;
    auto alloc = [&](size_t bytes) -> void* {
        void* r = (void*)p;
        p += (bytes + 255) & ~(size_t)255;
        return r;
    };
    bf16_t* h       = (bf16_t*)alloc((size_t)N * 128 * 2);
    bf16_t* zA      = (bf16_t*)alloc((size_t)N * 128 * 2);
    bf16_t* zB      = (bf16_t*)alloc((size_t)N * 128 * 2);
    bf16_t* hb      = (bf16_t*)alloc((size_t)N * 128 * 2);   // BN-activated nodes
    bf16_t* ebuf    = (bf16_t*)alloc((size_t)E * 128 * 2);   // dst-sorted
    int*    deg     = (int*)alloc((size_t)N * 4);
    int*    rowptr  = (int*)alloc(((size_t)N + 1) * 4);
    int*    cursor  = (int*)alloc((size_t)N * 4);
    int*    partials= (int*)alloc((size_t)N * 4);
    int*    bsums   = (int*)alloc((size_t)NB * 4);
    int*    boff    = (int*)alloc((size_t)NB * 4);
    int*    srcp    = (int*)alloc((size_t)E * 4);
    int*    epos    = (int*)alloc((size_t)E * 4);
    bf16_t* node_wt = (bf16_t*)alloc(128 * 32 * 2);
    bf16_t* ee_w1t  = (bf16_t*)alloc(128 * 32 * 2);
    bf16_t* ee_w2t  = (bf16_t*)alloc(128 * 128 * 2);
    bf16_t* cw1t    = (bf16_t*)alloc(3 * 128 * 128 * 2);
    bf16_t* cw2t    = (bf16_t*)alloc(3 * 128 * 128 * 2);
    float*  bns     = (float*)alloc(3 * 256 * 4);            // per-layer BN sums
    float*  gsum    = (float*)alloc((size_t)G * 128 * 4);
    float*  cnt     = (float*)alloc((size_t)G * 4);

    // --- CSR build (by dst); hist also warms edge_attr into MALL ---
    hipMemsetAsync(deg, 0, (size_t)N * 4, stream);
    hipMemsetAsync(bns, 0, 3 * 256 * 4, stream);
    hist_kernel<<<(E + 255) / 256, 256, 0, stream>>>(edge_index, deg, E, edge_attr);
    scanA_kernel<<<NB, 256, 0, stream>>>(deg, partials, bsums, N);
    scanB_kernel<<<1, 256, 0, stream>>>(bsums, boff, rowptr, NB, N);
    scanC_kernel<<<(N + 255) / 256, 256, 0, stream>>>(partials, boff, rowptr, cursor, N);
    scatter_kernel<<<(E + 255) / 256, 256, 0, stream>>>(edge_index, cursor, srcp, epos, E);

    // --- weight prep (single launch) ---
    prep_all_kernel<<<480, 256, 0, stream>>>(node_w, ee_w1, ee_w2, conv_w1, conv_w2,
                                             node_wt, ee_w1t, ee_w2t, cw1t, cw2t);

    // --- node encoder ---
    node_enc_kernel<<<(N + 127) / 128, 256, 0, stream>>>(x, N, node_wt, node_b, h);

    // --- edge encoder: sequential read, scatter write to CSR slots ---
    edge_mlp_kernel<<<(E + 63) / 64, 256, 0, stream>>>(
        edge_attr, E, ee_w1t, ee_b1, ee_w2t, ee_b2, epos, ebuf);

    // --- GINE layers (activation pre-materialized via bnx) ---
    const int nblk = (N + 31) / 32;
    const int bblk = ((N * 128 / 8) + 255) / 256;
    aggr_conv_kernel<<<nblk, 512, 0, stream>>>(
        h, ebuf, rowptr, srcp, N,
        cw1t + 0 * 16384, conv_b1 + 0 * 128, cw2t + 0 * 16384, conv_b2 + 0 * 128,
        zA, bns + 0);
    bnx_kernel<<<bblk, 256, 0, stream>>>(zA, bns + 0, bn_gamma + 0, bn_beta + 0, hb, N);
    aggr_conv_kernel<<<nblk, 512, 0, stream>>>(
        hb, ebuf, rowptr, srcp, N,
        cw1t + 1 * 16384, conv_b1 + 1 * 128, cw2t + 1 * 16384, conv_b2 + 1 * 128,
        zB, bns + 256);
    bnx_kernel<<<bblk, 256, 0, stream>>>(zB, bns + 256, bn_gamma + 128, bn_beta + 128, hb, N);
    aggr_conv_kernel<<<nblk, 512, 0, stream>>>(
        hb, ebuf, rowptr, srcp, N,
        cw1t + 2 * 16384, conv_b1 + 2 * 128, cw2t + 2 * 16384, conv_b2 + 2 * 128,
        zA, bns + 512);

    // --- pooling (BN+relu applied on read) + head ---
    hipMemsetAsync(gsum, 0, (size_t)G * 128 * 4, stream);
    hipMemsetAsync(cnt, 0, (size_t)G * 4, stream);
    pool_kernel<<<(N + 31) / 32, 128, 0, stream>>>(zA, bns + 512, bn_gamma + 256, bn_beta + 256,
                                                   batch, gsum, cnt, N);
    head_kernel<<<G, 128, 0, stream>>>(gsum, cnt, externals,
                                       ext_w1, ext_b1, ext_w2, ext_b2,
                                       reg_w1, reg_b1, reg_w2, reg_b2,
                                       (float*)d_out);
}